// Round 5
// baseline (3592.735 us; speedup 1.0000x reference)
//
#include <hip/hip_runtime.h>
#include <hip/hip_bf16.h>
#include <cmath>
#include <cstdint>

// Problem constants
#define BB   32
#define LL   512
#define DD   512
#define HH   8
#define DHH  64
#define DFF  2048
#define KMAXC 50

struct __align__(16) F4 { float v[4]; };
static __device__ __forceinline__ const F4* cf4(const float* p) { return reinterpret_cast<const F4*>(p); }
static __device__ __forceinline__ F4*       pf4(float* p)       { return reinterpret_cast<F4*>(p); }

// ---------------------------------------------------------------------------
// Tiled fp32 GEMM, 128x128 tile, 8x8 micro-tile per thread (2x2 of F4).
// C[M,N] = A[M,K] * B   (B is [K,N] if !TRANSB, [N,K] if TRANSB)
// optional RELU, optional residual: C = res + scale * result
// Requires M%128==0, N%128==0, K%16==0 (true for all call sites here).
// Arithmetic (per-wave, per K-step): 1024 FMA-instr (2048 VALU cyc) vs
// 64 ds_read_b128 (~10 KB distinct LDS) -> ~20 B/cyc/CU demand, far under
// the ~85-128 B/cyc LDS ceiling. VALU-bound: the fp32 roofline on CDNA4.
// ---------------------------------------------------------------------------
template<bool TRANSB, bool RELU, bool RES>
__global__ __launch_bounds__(256) void gemm_kernel(
    const float* __restrict__ A, int lda,
    const float* __restrict__ Bm, int ldb,
    float* __restrict__ C, int ldc,
    const float* __restrict__ res, const float* __restrict__ scale_ptr,
    int M, int N, int K)
{
  const int tid = threadIdx.x;
  const int tx = tid & 15, ty = tid >> 4;
  const int n0 = blockIdx.x * 128, m0 = blockIdx.y * 128;

  __shared__ __align__(16) float As[16][132];
  __shared__ __align__(16) float Bs[16][132];

  float acc[2][2][4][4] = {};

  const int sr  = tid >> 2;          // 0..63
  const int skc = (tid & 3) << 2;    // 0,4,8,12
  const int bkr = tid >> 5;          // 0..7
  const int bnc = (tid & 31) << 2;   // 0..124

  for (int k0 = 0; k0 < K; k0 += 16) {
    // stage A tile (transpose to [k][m]); rows m0+sr and m0+64+sr
#pragma unroll
    for (int rr = 0; rr < 2; ++rr) {
      F4 a = *cf4(&A[(size_t)(m0 + rr * 64 + sr) * lda + k0 + skc]);
      As[skc + 0][rr * 64 + sr] = a.v[0];
      As[skc + 1][rr * 64 + sr] = a.v[1];
      As[skc + 2][rr * 64 + sr] = a.v[2];
      As[skc + 3][rr * 64 + sr] = a.v[3];
    }
    if (TRANSB) { // B is [N,K]: stage transposed to [k][n]
#pragma unroll
      for (int rr = 0; rr < 2; ++rr) {
        F4 b = *cf4(&Bm[(size_t)(n0 + rr * 64 + sr) * ldb + k0 + skc]);
        Bs[skc + 0][rr * 64 + sr] = b.v[0];
        Bs[skc + 1][rr * 64 + sr] = b.v[1];
        Bs[skc + 2][rr * 64 + sr] = b.v[2];
        Bs[skc + 3][rr * 64 + sr] = b.v[3];
      }
    } else {      // B is [K,N]
#pragma unroll
      for (int rr = 0; rr < 2; ++rr) {
        int row = rr * 8 + bkr;
        *pf4(&Bs[row][bnc]) = *cf4(&Bm[(size_t)(k0 + row) * ldb + n0 + bnc]);
      }
    }
    __syncthreads();
#pragma unroll
    for (int kk = 0; kk < 16; ++kk) {
      F4 a0 = *cf4(&As[kk][ty * 4]);
      F4 a1 = *cf4(&As[kk][ty * 4 + 64]);
      F4 b0 = *cf4(&Bs[kk][tx * 4]);
      F4 b1 = *cf4(&Bs[kk][tx * 4 + 64]);
#pragma unroll
      for (int i = 0; i < 4; ++i) {
#pragma unroll
        for (int j = 0; j < 4; ++j) {
          acc[0][0][i][j] = fmaf(a0.v[i], b0.v[j], acc[0][0][i][j]);
          acc[0][1][i][j] = fmaf(a0.v[i], b1.v[j], acc[0][1][i][j]);
          acc[1][0][i][j] = fmaf(a1.v[i], b0.v[j], acc[1][0][i][j]);
          acc[1][1][i][j] = fmaf(a1.v[i], b1.v[j], acc[1][1][i][j]);
        }
      }
    }
    __syncthreads();
  }

  float scl = 1.0f;
  if (RES) scl = scale_ptr ? *scale_ptr : 1.0f;
#pragma unroll
  for (int ii = 0; ii < 2; ++ii) {
#pragma unroll
    for (int i = 0; i < 4; ++i) {
      const size_t row = (size_t)(m0 + ii * 64 + ty * 4 + i);
#pragma unroll
      for (int jj = 0; jj < 2; ++jj) {
        const int col = n0 + jj * 64 + tx * 4;
        F4 o;
#pragma unroll
        for (int j = 0; j < 4; ++j) {
          float v = acc[ii][jj][i][j];
          if (RELU) v = fmaxf(v, 0.0f);
          o.v[j] = v;
        }
        if (RES) {
          F4 r = *cf4(&res[row * ldc + col]);
#pragma unroll
          for (int j = 0; j < 4; ++j) o.v[j] = fmaf(o.v[j], scl, r.v[j]);
        }
        *pf4(&C[row * ldc + col]) = o;
      }
    }
  }
}

// ---------------------------------------------------------------------------
// Flash-style fp32 attention, dh=64, Lq=Lk=512, heads packed in D.
// Block: 256 thr, 64 q-rows; K-tiles of 32. grid = (L/64, B*H).
// O may alias Q: each block reads only its own (rows q0..q0+63) x (own
// head's 64 cols) slice, staged to LDS before any write; all other blocks
// touch disjoint row or column ranges.
// ---------------------------------------------------------------------------
__global__ __launch_bounds__(256) void attn_kernel(
    const float* __restrict__ Q, const float* __restrict__ K,
    const float* __restrict__ V, float* __restrict__ O)
{
  const int bh = blockIdx.y;
  const int b = bh >> 3, h = bh & 7;
  const int q0 = blockIdx.x * 64;
  const int tid = threadIdx.x;
  const int tx = tid & 15, ty = tid >> 4;

  __shared__ __align__(16) float Qs[64][68];
  __shared__ __align__(16) float Ks[32][68];
  __shared__ __align__(16) float Vs[32][68];
  __shared__ __align__(16) float Ps[64][36];

  const size_t base = ((size_t)b * LL) * DD + (size_t)h * DHH;

  // stage Q (scaled by 1/sqrt(64) = 0.125)
#pragma unroll
  for (int rr = 0; rr < 4; ++rr) {
    int row = rr * 16 + (tid >> 4);
    int col = (tid & 15) * 4;
    F4 a = *cf4(&Q[base + (size_t)(q0 + row) * DD + col]);
#pragma unroll
    for (int c = 0; c < 4; ++c) a.v[c] *= 0.125f;
    *pf4(&Qs[row][col]) = a;
  }

  float m[4], l[4], o[4][4];
#pragma unroll
  for (int i = 0; i < 4; ++i) {
    m[i] = -1e30f; l[i] = 0.0f;
#pragma unroll
    for (int j = 0; j < 4; ++j) o[i][j] = 0.0f;
  }

  const int r0 = ty * 4, kc0 = tx * 2, c0 = tx * 4;

  for (int kt = 0; kt < 16; ++kt) {
    // stage K,V tile (32 rows)
#pragma unroll
    for (int rr = 0; rr < 2; ++rr) {
      int row = rr * 16 + (tid >> 4);
      int col = (tid & 15) * 4;
      *pf4(&Ks[row][col]) = *cf4(&K[base + (size_t)(kt * 32 + row) * DD + col]);
      *pf4(&Vs[row][col]) = *cf4(&V[base + (size_t)(kt * 32 + row) * DD + col]);
    }
    __syncthreads();

    // S = Q * K^T  (each thread: 4 rows x 2 kcols)
    float s[4][2] = {};
#pragma unroll
    for (int d4 = 0; d4 < 16; ++d4) {
      F4 k0v = *cf4(&Ks[kc0][d4 * 4]);
      F4 k1v = *cf4(&Ks[kc0 + 1][d4 * 4]);
#pragma unroll
      for (int i = 0; i < 4; ++i) {
        F4 qv = *cf4(&Qs[r0 + i][d4 * 4]);
#pragma unroll
        for (int c = 0; c < 4; ++c) {
          s[i][0] = fmaf(qv.v[c], k0v.v[c], s[i][0]);
          s[i][1] = fmaf(qv.v[c], k1v.v[c], s[i][1]);
        }
      }
    }

    // online softmax (row stats across the 16-lane tx group)
#pragma unroll
    for (int i = 0; i < 4; ++i) {
      float mloc = fmaxf(s[i][0], s[i][1]);
      for (int off = 1; off < 16; off <<= 1) mloc = fmaxf(mloc, __shfl_xor(mloc, off, 16));
      float mnew = fmaxf(m[i], mloc);
      float p0 = __expf(s[i][0] - mnew);
      float p1 = __expf(s[i][1] - mnew);
      float alpha = __expf(m[i] - mnew);
      float ls = p0 + p1;
      for (int off = 1; off < 16; off <<= 1) ls += __shfl_xor(ls, off, 16);
      l[i] = l[i] * alpha + ls;
      m[i] = mnew;
#pragma unroll
      for (int j = 0; j < 4; ++j) o[i][j] *= alpha;
      Ps[r0 + i][kc0] = p0;
      Ps[r0 + i][kc0 + 1] = p1;
    }
    __syncthreads();

    // O += P * V
#pragma unroll
    for (int k4 = 0; k4 < 8; ++k4) {
      F4 vv[4];
#pragma unroll
      for (int jj = 0; jj < 4; ++jj) vv[jj] = *cf4(&Vs[k4 * 4 + jj][c0]);
#pragma unroll
      for (int i = 0; i < 4; ++i) {
        F4 p = *cf4(&Ps[r0 + i][k4 * 4]);
#pragma unroll
        for (int jj = 0; jj < 4; ++jj)
#pragma unroll
          for (int j = 0; j < 4; ++j)
            o[i][j] = fmaf(p.v[jj], vv[jj].v[j], o[i][j]);
      }
    }
    __syncthreads();
  }

#pragma unroll
  for (int i = 0; i < 4; ++i) {
    float inv = 1.0f / l[i];
    F4 ov;
#pragma unroll
    for (int j = 0; j < 4; ++j) ov.v[j] = o[i][j] * inv;
    *pf4(&O[base + (size_t)(q0 + r0 + i) * DD + c0]) = ov;
  }
}

// ---------------------------------------------------------------------------
// Kernel-size predictor head. One block per sample.
// ---------------------------------------------------------------------------
__global__ __launch_bounds__(256) void kp_head_kernel(
    const float* __restrict__ x, const float* __restrict__ w1,
    const float* __restrict__ b1, const float* __restrict__ w2,
    const float* __restrict__ b2, int* __restrict__ kout)
{
  const int b = blockIdx.x, tid = threadIdx.x;
  __shared__ float xg[DD];
  __shared__ float h1s[256];
  __shared__ float red[256];
  const float* xb = x + (size_t)b * LL * DD;

  for (int d = tid; d < DD; d += 256) {
    float s = 0.0f;
    for (int l = 0; l < LL; ++l) s += xb[(size_t)l * DD + d];
    xg[d] = s * (1.0f / (float)LL);
  }
  __syncthreads();
  {
    float s = b1[tid];
    for (int d = 0; d < DD; ++d) s = fmaf(xg[d], w1[d * 256 + tid], s);
    h1s[tid] = fmaxf(s, 0.0f);
  }
  __syncthreads();
  red[tid] = h1s[tid] * w2[tid];
  __syncthreads();
  for (int st = 128; st > 0; st >>= 1) {
    if (tid < st) red[tid] += red[tid + st];
    __syncthreads();
  }
  if (tid == 0) {
    float z = red[0] + b2[0];
    float kf = 45.0f / (1.0f + expf(-z)) + 5.0f;
    int k = (int)rintf(kf);          // round-half-to-even, matches jnp.round
    if (k > 50) k = 50;
    if (k < 3) k = 3;
    if ((k & 1) == 0) k -= 1;
    if (k < 3) k = 3;
    kout[b] = k;
  }
}

// Per (b,d) softmax over first k taps of dw[d,:]; store transposed [B][KMAX][D]
__global__ __launch_bounds__(256) void softmax_w_kernel(
    const float* __restrict__ dw, const int* __restrict__ kvals,
    float* __restrict__ wT)
{
  const int b = blockIdx.y;
  const int d = blockIdx.x * 256 + threadIdx.x;
  const int k = kvals[b];
  const float* row = dw + (size_t)d * KMAXC;
  float mx = -1e30f;
  for (int j = 0; j < k; ++j) mx = fmaxf(mx, row[j]);
  float ssum = 0.0f;
  for (int j = 0; j < k; ++j) ssum += __expf(row[j] - mx);
  float inv = 1.0f / ssum;
  float* w = wT + (size_t)b * KMAXC * DD + d;
  for (int j = 0; j < k; ++j) w[(size_t)j * DD] = __expf(row[j] - mx) * inv;
}

// trend[b,l,d] = sum_{j<k} wT[b,j,d] * x[b, clamp(l-half+j), d]
__global__ __launch_bounds__(512) void trend_kernel(
    const float* __restrict__ xin, const float* __restrict__ wT,
    const int* __restrict__ kvals, float* __restrict__ tr)
{
  const int b = blockIdx.y, l = blockIdx.x, d = threadIdx.x;
  const int k = kvals[b], half = k >> 1;
  const float* xb = xin + (size_t)b * LL * DD;
  const float* w = wT + (size_t)b * KMAXC * DD + d;
  float t = 0.0f;
  for (int j = 0; j < k; ++j) {
    int li = l - half + j;
    li = li < 0 ? 0 : (li > LL - 1 ? LL - 1 : li);
    t = fmaf(w[(size_t)j * DD], xb[(size_t)li * DD + d], t);
  }
  tr[((size_t)b * LL + l) * DD + d] = t;
}

// xout = xin - tr;  tacc = (first ? tr : tacc + tr)   (F4-vectorized)
__global__ __launch_bounds__(256) void apply_kernel(
    const float* __restrict__ xin, const float* __restrict__ tr,
    float* __restrict__ xout, float* __restrict__ tacc, int first)
{
  size_t i = (size_t)blockIdx.x * blockDim.x + threadIdx.x; // F4 idx
  F4 xv = cf4(xin)[i];
  F4 tv = cf4(tr)[i];
  F4 o, a;
  if (first) {
#pragma unroll
    for (int c = 0; c < 4; ++c) { o.v[c] = xv.v[c] - tv.v[c]; a.v[c] = tv.v[c]; }
  } else {
    F4 ta = cf4((const float*)tacc)[i];
#pragma unroll
    for (int c = 0; c < 4; ++c) { o.v[c] = xv.v[c] - tv.v[c]; a.v[c] = ta.v[c] + tv.v[c]; }
  }
  pf4(xout)[i] = o;
  pf4(tacc)[i] = a;
}

// aaug[b,l, t*D+d] = tacc[b, (l-1+t) mod L, d]   (circular)
__global__ __launch_bounds__(512) void build_aaug_kernel(
    const float* __restrict__ tacc, float* __restrict__ aaug)
{
  const int b = blockIdx.y, l = blockIdx.x, d = threadIdx.x;
  float* outp = aaug + ((size_t)b * LL + l) * (3 * DD);
  const float* tb = tacc + (size_t)b * LL * DD;
#pragma unroll
  for (int t = 0; t < 3; ++t) {
    int li = (l - 1 + t + LL) & (LL - 1);
    outp[t * DD + d] = tb[(size_t)li * DD + d];
  }
}

// w1r[o, t*D+d] = proj_w1[o, d, t]
__global__ __launch_bounds__(256) void rearrange_w1_kernel(
    const float* __restrict__ pw1, float* __restrict__ w1r)
{
  const int o = blockIdx.x;
  for (int i = threadIdx.x; i < 3 * DD; i += 256) {
    int t = i / DD, d = i - t * DD;
    w1r[(size_t)o * (3 * DD) + i] = pw1[(size_t)o * (3 * DD) + d * 3 + t];
  }
}

// ---------------------------------------------------------------------------
extern "C" void kernel_launch(void* const* d_in, const int* in_sizes, int n_in,
                              void* d_out, int out_size, void* d_ws, size_t ws_size,
                              hipStream_t stream)
{
  const float* x      = (const float*)d_in[0];
  const float* cross  = (const float*)d_in[1];
  const float* wq_s   = (const float*)d_in[2];
  const float* wk_s   = (const float*)d_in[3];
  const float* wv_s   = (const float*)d_in[4];
  const float* wo_s   = (const float*)d_in[5];
  const float* wq_c   = (const float*)d_in[6];
  const float* wk_c   = (const float*)d_in[7];
  const float* wv_c   = (const float*)d_in[8];
  const float* wo_c   = (const float*)d_in[9];
  const float* conv1  = (const float*)d_in[10];
  const float* conv2  = (const float*)d_in[11];
  const float* dw     = (const float*)d_in[12];
  const float* kp_w1  = (const float*)d_in[13];
  const float* kp_b1  = (const float*)d_in[14];
  const float* kp_w2  = (const float*)d_in[15];
  const float* kp_b2  = (const float*)d_in[16];
  const float* pw1    = (const float*)d_in[17];
  const float* pw2    = (const float*)d_in[18];
  const float* sscale = (const float*)d_in[19];
  const float* cscale = (const float*)d_in[20];

  float* out = (float*)d_out;
  float* ws  = (float*)d_ws;

  const size_t NBLD = (size_t)BB * LL * DD;   // 8,388,608 floats (32 MiB)
  // Workspace layout (~195 MB), phase-based reuse:
  float* xcur   = ws;                // persistent residual stream
  float* tacc   = ws + NBLD;         // persistent trend accumulator
  float* big    = ws + 2 * NBLD;     // 4*NBLD region, reused per phase
  float* qb     = big;
  float* kb     = big + NBLD;
  float* vb     = big + 2 * NBLD;
  float* attno  = big;               // attention O in-place over Q (safe: see attn_kernel)
  float* hidden = big;               // FFN hidden: exactly 4*NBLD
  float* aaug   = big;               // [B*L, 3D]: 3*NBLD
  float* hconv  = big + 3 * NBLD;
  float* trendb = big;               // trend scratch (region free during decomp)
  float* smallp = ws + 6 * NBLD;
  float* wT     = smallp;                    // B*KMAX*D = 819200
  int*   kvals  = (int*)(smallp + 819200);   // 32 ints
  float* w1r    = smallp + 819200 + 64;      // 512*1536

  const int M = BB * LL;  // 16384
  const dim3 g512(4, 128), gFF1(16, 128), gBL(LL, BB), gSM(2, BB);

  // ---- self attention ----
  gemm_kernel<false,false,false><<<g512,256,0,stream>>>(x,DD, wq_s,DD, qb,DD, nullptr,nullptr, M,DD,DD);
  gemm_kernel<false,false,false><<<g512,256,0,stream>>>(x,DD, wk_s,DD, kb,DD, nullptr,nullptr, M,DD,DD);
  gemm_kernel<false,false,false><<<g512,256,0,stream>>>(x,DD, wv_s,DD, vb,DD, nullptr,nullptr, M,DD,DD);
  attn_kernel<<<dim3(8, BB*HH),256,0,stream>>>(qb, kb, vb, attno);
  gemm_kernel<false,false,true ><<<g512,256,0,stream>>>(attno,DD, wo_s,DD, xcur,DD, x, sscale, M,DD,DD);

  // ---- decomp 1 ----
  kp_head_kernel<<<BB,256,0,stream>>>(xcur, kp_w1, kp_b1, kp_w2, kp_b2, kvals);
  softmax_w_kernel<<<gSM,256,0,stream>>>(dw, kvals, wT);
  trend_kernel<<<gBL,512,0,stream>>>(xcur, wT, kvals, trendb);
  apply_kernel<<<8192,256,0,stream>>>(xcur, trendb, xcur, tacc, 1);

  // ---- cross attention ----
  gemm_kernel<false,false,false><<<g512,256,0,stream>>>(xcur,DD, wq_c,DD, qb,DD, nullptr,nullptr, M,DD,DD);
  gemm_kernel<false,false,false><<<g512,256,0,stream>>>(cross,DD, wk_c,DD, kb,DD, nullptr,nullptr, M,DD,DD);
  gemm_kernel<false,false,false><<<g512,256,0,stream>>>(cross,DD, wv_c,DD, vb,DD, nullptr,nullptr, M,DD,DD);
  attn_kernel<<<dim3(8, BB*HH),256,0,stream>>>(qb, kb, vb, attno);
  gemm_kernel<false,false,true ><<<g512,256,0,stream>>>(attno,DD, wo_c,DD, xcur,DD, xcur, cscale, M,DD,DD);

  // ---- decomp 2 ----
  kp_head_kernel<<<BB,256,0,stream>>>(xcur, kp_w1+131072, kp_b1+256, kp_w2+256, kp_b2+1, kvals);
  softmax_w_kernel<<<gSM,256,0,stream>>>(dw+25600, kvals, wT);
  trend_kernel<<<gBL,512,0,stream>>>(xcur, wT, kvals, trendb);
  apply_kernel<<<8192,256,0,stream>>>(xcur, trendb, xcur, tacc, 0);

  // ---- conv FFN ----
  gemm_kernel<true ,true ,false><<<gFF1,256,0,stream>>>(xcur,DD, conv1,DD, hidden,DFF, nullptr,nullptr, M,DFF,DD);
  gemm_kernel<true ,false,true ><<<g512,256,0,stream>>>(hidden,DFF, conv2,DFF, xcur,DD, xcur, nullptr, M,DD,DFF);

  // ---- decomp 3 (x3 straight to d_out) ----
  kp_head_kernel<<<BB,256,0,stream>>>(xcur, kp_w1+262144, kp_b1+512, kp_w2+512, kp_b2+2, kvals);
  softmax_w_kernel<<<gSM,256,0,stream>>>(dw+51200, kvals, wT);
  trend_kernel<<<gBL,512,0,stream>>>(xcur, wT, kvals, trendb);
  apply_kernel<<<8192,256,0,stream>>>(xcur, trendb, out, tacc, 0);

  // ---- trend projection ----
  build_aaug_kernel<<<gBL,512,0,stream>>>(tacc, aaug);
  rearrange_w1_kernel<<<512,256,0,stream>>>(pw1, w1r);
  gemm_kernel<true ,true ,false><<<g512,256,0,stream>>>(aaug,3*DD, w1r,3*DD, hconv,DD, nullptr,nullptr, M,DD,3*DD);
  gemm_kernel<true ,false,false><<<g512,256,0,stream>>>(hconv,DD, pw2,DD, out+NBLD,DD, nullptr,nullptr, M,DD,DD);
}

// Round 8
// 2229.376 us; speedup vs baseline: 1.6115x; 1.6115x over previous
//
#include <hip/hip_runtime.h>
#include <hip/hip_bf16.h>
#include <cmath>
#include <cstdint>

// Problem constants
#define BB   32
#define LL   512
#define DD   512
#define HH   8
#define DHH  64
#define DFF  2048
#define KMAXC 50

struct __align__(16) F4 { float v[4]; };
static __device__ __forceinline__ const F4* cf4(const float* p) { return reinterpret_cast<const F4*>(p); }
static __device__ __forceinline__ F4*       pf4(float* p)       { return reinterpret_cast<F4*>(p); }

typedef __attribute__((ext_vector_type(8))) short short8;   // 8 bf16 = 4 VGPR (MFMA frag)
typedef __attribute__((ext_vector_type(4))) float f32x4;    // MFMA accumulator

// fp32 -> bf16 round-to-nearest-even (bit trick), and back (exact)
static __device__ __forceinline__ ushort f2bf(float f) {
  unsigned u = __float_as_uint(f);
  return (ushort)((u + 0x7FFFu + ((u >> 16) & 1u)) >> 16);
}
static __device__ __forceinline__ float bf2f(ushort h) {
  return __uint_as_float(((unsigned)h) << 16);
}

// ---------------------------------------------------------------------------
// Split-bf16 MFMA GEMM.  C[M,N] = A[M,K] (fp32) * W  where W is pre-split
// bf16 planes [2][N][K] (hi, lo).  x = hi + lo; x*y = hihi + hilo + lohi
// (lo*lo dropped, ~2^-18 rel) -> 3 MFMAs per 16x16x32 tile, fp32 accum.
// Tile 128x128, BK=32, 4 waves; each wave owns a 64x64 quadrant = 4x4 MFMA
// tiles.  A is converted to hi/lo during staging; W is copied bf16->LDS.
// LDS rows padded 32->40 shorts: frag ds_read_b128 start-banks partition
// 32 banks with 2-way aliasing only (free per m136).
// C/D layout (HW-verified m89/m91): col = lane&15, row = (lane>>4)*4 + reg.
// A/B per-lane k-order: identical bijection on both operands cancels in sum-k.
// Requires M%128==0, N%128==0, K%32==0 (true at all call sites).
// ---------------------------------------------------------------------------
template<bool RELU, bool RES>
__global__ __launch_bounds__(256) void gemm_bf(
    const float* __restrict__ A, int lda,
    const short* __restrict__ W,          // [2][N][K] bf16 planes
    float* __restrict__ C, int ldc,
    const float* __restrict__ res, const float* __restrict__ scale_ptr,
    int M, int N, int K)
{
  const int tid = threadIdx.x;
  const int n0 = blockIdx.x * 128, m0 = blockIdx.y * 128;

  __shared__ short As[2][128][40];   // [hi/lo][m][k] padded
  __shared__ short Bs[2][128][40];   // [hi/lo][n][k] padded

  const int lane = tid & 63;
  const int wid  = tid >> 6;
  const int wr   = (wid >> 1) * 64;      // wave quadrant row
  const int wc   = (wid & 1) * 64;       // wave quadrant col
  const int fr   = lane & 15;            // row/col within 16x16 tile
  const int fkb  = (lane >> 4) * 8;      // k fragment offset (shorts)

  f32x4 acc[4][4] = {};

  const int srow = tid >> 1;             // 0..127 (m-row or n-row)
  const int skh  = (tid & 1) << 4;       // 0 or 16 (k half)

  const size_t wplane = (size_t)N * K;   // lo-plane offset in shorts

  for (int k0 = 0; k0 < K; k0 += 32) {
    // ---- stage A (fp32 -> hi/lo bf16): row srow, k [skh, skh+16) ----
    {
      const float* ap = A + (size_t)(m0 + srow) * lda + (k0 + skh);
#pragma unroll
      for (int q = 0; q < 2; ++q) {
        F4 va = cf4(ap)[2 * q];
        F4 vb = cf4(ap)[2 * q + 1];
        short8 hh, ll;
#pragma unroll
        for (int e = 0; e < 4; ++e) {
          ushort h0 = f2bf(va.v[e]);
          hh[e]     = (short)h0;
          ll[e]     = (short)f2bf(va.v[e] - bf2f(h0));
          ushort h1 = f2bf(vb.v[e]);
          hh[4 + e] = (short)h1;
          ll[4 + e] = (short)f2bf(vb.v[e] - bf2f(h1));
        }
        *(short8*)&As[0][srow][skh + q * 8] = hh;
        *(short8*)&As[1][srow][skh + q * 8] = ll;
      }
    }
    // ---- stage W (already bf16 split): row srow = n, k [skh, skh+16) ----
    {
      const short* wp = W + (size_t)(n0 + srow) * K + (k0 + skh);
      *(short8*)&Bs[0][srow][skh]     = *(const short8*)wp;
      *(short8*)&Bs[0][srow][skh + 8] = *(const short8*)(wp + 8);
      *(short8*)&Bs[1][srow][skh]     = *(const short8*)(wp + wplane);
      *(short8*)&Bs[1][srow][skh + 8] = *(const short8*)(wp + wplane + 8);
    }
    __syncthreads();

    // ---- 4x4 tiles x 3 MFMAs ----
    short8 bhi[4], blo[4];
#pragma unroll
    for (int j = 0; j < 4; ++j) {
      bhi[j] = *(const short8*)&Bs[0][wc + j * 16 + fr][fkb];
      blo[j] = *(const short8*)&Bs[1][wc + j * 16 + fr][fkb];
    }
#pragma unroll
    for (int i = 0; i < 4; ++i) {
      short8 ahi = *(const short8*)&As[0][wr + i * 16 + fr][fkb];
      short8 alo = *(const short8*)&As[1][wr + i * 16 + fr][fkb];
#pragma unroll
      for (int j = 0; j < 4; ++j) {
        acc[i][j] = __builtin_amdgcn_mfma_f32_16x16x32_bf16(alo, bhi[j], acc[i][j], 0, 0, 0);
        acc[i][j] = __builtin_amdgcn_mfma_f32_16x16x32_bf16(ahi, blo[j], acc[i][j], 0, 0, 0);
        acc[i][j] = __builtin_amdgcn_mfma_f32_16x16x32_bf16(ahi, bhi[j], acc[i][j], 0, 0, 0);
      }
    }
    __syncthreads();
  }

  // ---- epilogue ----
  float scl = 1.0f;
  if (RES) scl = scale_ptr ? *scale_ptr : 1.0f;
  const int er = (lane >> 4) << 2;       // 0,4,8,12
#pragma unroll
  for (int i = 0; i < 4; ++i) {
#pragma unroll
    for (int p = 0; p < 4; ++p) {
      const size_t row = (size_t)(m0 + wr + i * 16 + er + p);
#pragma unroll
      for (int j = 0; j < 4; ++j) {
        const int col = n0 + wc + j * 16 + fr;
        float v = acc[i][j][p];
        if (RELU) v = fmaxf(v, 0.0f);
        if (RES)  v = fmaf(v, scl, res[row * (size_t)ldc + col]);
        C[row * (size_t)ldc + col] = v;
      }
    }
  }
}

// ---------------------------------------------------------------------------
// Weight prep: [K][N] fp32 -> [2][N][K] bf16 (transpose + split), LDS-tiled.
// ---------------------------------------------------------------------------
__global__ __launch_bounds__(256) void conv_w_t_kernel(
    const float* __restrict__ W, short* __restrict__ out, int K, int N)
{
  __shared__ float t[32][33];
  const int k0 = blockIdx.x * 32, n0 = blockIdx.y * 32;
  const int tx = threadIdx.x & 31, ty = threadIdx.x >> 5;   // 32 x 8
  for (int r = ty; r < 32; r += 8)
    t[r][tx] = W[(size_t)(k0 + r) * N + n0 + tx];
  __syncthreads();
  const size_t plane = (size_t)N * K;
  for (int r = ty; r < 32; r += 8) {
    float f = t[tx][r];                       // W[k0+tx][n0+r]
    ushort h = f2bf(f);
    out[(size_t)(n0 + r) * K + k0 + tx]         = (short)h;
    out[plane + (size_t)(n0 + r) * K + k0 + tx] = (short)f2bf(f - bf2f(h));
  }
}

// Weight prep: [N][K] fp32 -> [2][N][K] bf16 (split only, elementwise).
__global__ __launch_bounds__(256) void conv_w_kernel(
    const float* __restrict__ W, short* __restrict__ out, size_t NK)
{
  size_t i = (size_t)blockIdx.x * 256 + threadIdx.x;
  float f = W[i];
  ushort h = f2bf(f);
  out[i]      = (short)h;
  out[NK + i] = (short)f2bf(f - bf2f(h));
}

// proj_w1 [COUT][D][3] -> split bf16 [2][COUT][3*D] with w1r[o][t*D+d] layout
__global__ __launch_bounds__(256) void rearrange_w1_bf_kernel(
    const float* __restrict__ pw1, short* __restrict__ out)
{
  const int o = blockIdx.x;
  const size_t plane = (size_t)DD * (3 * DD);
  for (int i = threadIdx.x; i < 3 * DD; i += 256) {
    int t = i / DD, d = i - t * DD;
    float f = pw1[(size_t)o * (3 * DD) + d * 3 + t];
    ushort h = f2bf(f);
    out[(size_t)o * (3 * DD) + i]         = (short)h;
    out[plane + (size_t)o * (3 * DD) + i] = (short)f2bf(f - bf2f(h));
  }
}

// ---------------------------------------------------------------------------
// Flash-style fp32 attention, dh=64, Lq=Lk=512, heads packed in D.
// Block: 256 thr, 64 q-rows; K-tiles of 32. grid = (L/64, B*H).
// O may alias Q (block reads only its own rows x own head's cols, staged
// to LDS before any write).
// ---------------------------------------------------------------------------
__global__ __launch_bounds__(256) void attn_kernel(
    const float* __restrict__ Q, const float* __restrict__ K,
    const float* __restrict__ V, float* __restrict__ O)
{
  const int bh = blockIdx.y;
  const int b = bh >> 3, h = bh & 7;
  const int q0 = blockIdx.x * 64;
  const int tid = threadIdx.x;
  const int tx = tid & 15, ty = tid >> 4;

  __shared__ __align__(16) float Qs[64][68];
  __shared__ __align__(16) float Ks[32][68];
  __shared__ __align__(16) float Vs[32][68];
  __shared__ __align__(16) float Ps[64][36];

  const size_t base = ((size_t)b * LL) * DD + (size_t)h * DHH;

#pragma unroll
  for (int rr = 0; rr < 4; ++rr) {
    int row = rr * 16 + (tid >> 4);
    int col = (tid & 15) * 4;
    F4 a = *cf4(&Q[base + (size_t)(q0 + row) * DD + col]);
#pragma unroll
    for (int c = 0; c < 4; ++c) a.v[c] *= 0.125f;
    *pf4(&Qs[row][col]) = a;
  }

  float m[4], l[4], o[4][4];
#pragma unroll
  for (int i = 0; i < 4; ++i) {
    m[i] = -1e30f; l[i] = 0.0f;
#pragma unroll
    for (int j = 0; j < 4; ++j) o[i][j] = 0.0f;
  }

  const int r0 = ty * 4, kc0 = tx * 2, c0 = tx * 4;

  for (int kt = 0; kt < 16; ++kt) {
#pragma unroll
    for (int rr = 0; rr < 2; ++rr) {
      int row = rr * 16 + (tid >> 4);
      int col = (tid & 15) * 4;
      *pf4(&Ks[row][col]) = *cf4(&K[base + (size_t)(kt * 32 + row) * DD + col]);
      *pf4(&Vs[row][col]) = *cf4(&V[base + (size_t)(kt * 32 + row) * DD + col]);
    }
    __syncthreads();

    float s[4][2] = {};
#pragma unroll
    for (int d4 = 0; d4 < 16; ++d4) {
      F4 k0v = *cf4(&Ks[kc0][d4 * 4]);
      F4 k1v = *cf4(&Ks[kc0 + 1][d4 * 4]);
#pragma unroll
      for (int i = 0; i < 4; ++i) {
        F4 qv = *cf4(&Qs[r0 + i][d4 * 4]);
#pragma unroll
        for (int c = 0; c < 4; ++c) {
          s[i][0] = fmaf(qv.v[c], k0v.v[c], s[i][0]);
          s[i][1] = fmaf(qv.v[c], k1v.v[c], s[i][1]);
        }
      }
    }

#pragma unroll
    for (int i = 0; i < 4; ++i) {
      float mloc = fmaxf(s[i][0], s[i][1]);
      for (int off = 1; off < 16; off <<= 1) mloc = fmaxf(mloc, __shfl_xor(mloc, off, 16));
      float mnew = fmaxf(m[i], mloc);
      float p0 = __expf(s[i][0] - mnew);
      float p1 = __expf(s[i][1] - mnew);
      float alpha = __expf(m[i] - mnew);
      float ls = p0 + p1;
      for (int off = 1; off < 16; off <<= 1) ls += __shfl_xor(ls, off, 16);
      l[i] = l[i] * alpha + ls;
      m[i] = mnew;
#pragma unroll
      for (int j = 0; j < 4; ++j) o[i][j] *= alpha;
      Ps[r0 + i][kc0] = p0;
      Ps[r0 + i][kc0 + 1] = p1;
    }
    __syncthreads();

#pragma unroll
    for (int k4 = 0; k4 < 8; ++k4) {
      F4 vv[4];
#pragma unroll
      for (int jj = 0; jj < 4; ++jj) vv[jj] = *cf4(&Vs[k4 * 4 + jj][c0]);
#pragma unroll
      for (int i = 0; i < 4; ++i) {
        F4 p = *cf4(&Ps[r0 + i][k4 * 4]);
#pragma unroll
        for (int jj = 0; jj < 4; ++jj)
#pragma unroll
          for (int j = 0; j < 4; ++j)
            o[i][j] = fmaf(p.v[jj], vv[jj].v[j], o[i][j]);
      }
    }
    __syncthreads();
  }

#pragma unroll
  for (int i = 0; i < 4; ++i) {
    float inv = 1.0f / l[i];
    F4 ov;
#pragma unroll
    for (int j = 0; j < 4; ++j) ov.v[j] = o[i][j] * inv;
    *pf4(&O[base + (size_t)(q0 + r0 + i) * DD + c0]) = ov;
  }
}

// ---------------------------------------------------------------------------
// Kernel-size predictor head. One block per sample.
// ---------------------------------------------------------------------------
__global__ __launch_bounds__(256) void kp_head_kernel(
    const float* __restrict__ x, const float* __restrict__ w1,
    const float* __restrict__ b1, const float* __restrict__ w2,
    const float* __restrict__ b2, int* __restrict__ kout)
{
  const int b = blockIdx.x, tid = threadIdx.x;
  __shared__ float xg[DD];
  __shared__ float h1s[256];
  __shared__ float red[256];
  const float* xb = x + (size_t)b * LL * DD;

  for (int d = tid; d < DD; d += 256) {
    float s = 0.0f;
    for (int l = 0; l < LL; ++l) s += xb[(size_t)l * DD + d];
    xg[d] = s * (1.0f / (float)LL);
  }
  __syncthreads();
  {
    float s = b1[tid];
    for (int d = 0; d < DD; ++d) s = fmaf(xg[d], w1[d * 256 + tid], s);
    h1s[tid] = fmaxf(s, 0.0f);
  }
  __syncthreads();
  red[tid] = h1s[tid] * w2[tid];
  __syncthreads();
  for (int st = 128; st > 0; st >>= 1) {
    if (tid < st) red[tid] += red[tid + st];
    __syncthreads();
  }
  if (tid == 0) {
    float z = red[0] + b2[0];
    float kf = 45.0f / (1.0f + expf(-z)) + 5.0f;
    int k = (int)rintf(kf);          // round-half-to-even, matches jnp.round
    if (k > 50) k = 50;
    if (k < 3) k = 3;
    if ((k & 1) == 0) k -= 1;
    if (k < 3) k = 3;
    kout[b] = k;
  }
}

// Per (b,d) softmax over first k taps of dw[d,:]; store transposed [B][KMAX][D]
__global__ __launch_bounds__(256) void softmax_w_kernel(
    const float* __restrict__ dw, const int* __restrict__ kvals,
    float* __restrict__ wT)
{
  const int b = blockIdx.y;
  const int d = blockIdx.x * 256 + threadIdx.x;
  const int k = kvals[b];
  const float* row = dw + (size_t)d * KMAXC;
  float mx = -1e30f;
  for (int j = 0; j < k; ++j) mx = fmaxf(mx, row[j]);
  float ssum = 0.0f;
  for (int j = 0; j < k; ++j) ssum += __expf(row[j] - mx);
  float inv = 1.0f / ssum;
  float* w = wT + (size_t)b * KMAXC * DD + d;
  for (int j = 0; j < k; ++j) w[(size_t)j * DD] = __expf(row[j] - mx) * inv;
}

// trend[b,l,d] = sum_{j<k} wT[b,j,d] * x[b, clamp(l-half+j), d]
__global__ __launch_bounds__(512) void trend_kernel(
    const float* __restrict__ xin, const float* __restrict__ wT,
    const int* __restrict__ kvals, float* __restrict__ tr)
{
  const int b = blockIdx.y, l = blockIdx.x, d = threadIdx.x;
  const int k = kvals[b], half = k >> 1;
  const float* xb = xin + (size_t)b * LL * DD;
  const float* w = wT + (size_t)b * KMAXC * DD + d;
  float t = 0.0f;
  for (int j = 0; j < k; ++j) {
    int li = l - half + j;
    li = li < 0 ? 0 : (li > LL - 1 ? LL - 1 : li);
    t = fmaf(w[(size_t)j * DD], xb[(size_t)li * DD + d], t);
  }
  tr[((size_t)b * LL + l) * DD + d] = t;
}

// xout = xin - tr;  tacc = (first ? tr : tacc + tr)
__global__ __launch_bounds__(256) void apply_kernel(
    const float* __restrict__ xin, const float* __restrict__ tr,
    float* __restrict__ xout, float* __restrict__ tacc, int first)
{
  size_t i = (size_t)blockIdx.x * blockDim.x + threadIdx.x; // F4 idx
  F4 xv = cf4(xin)[i];
  F4 tv = cf4(tr)[i];
  F4 o, a;
  if (first) {
#pragma unroll
    for (int c = 0; c < 4; ++c) { o.v[c] = xv.v[c] - tv.v[c]; a.v[c] = tv.v[c]; }
  } else {
    F4 ta = cf4((const float*)tacc)[i];
#pragma unroll
    for (int c = 0; c < 4; ++c) { o.v[c] = xv.v[c] - tv.v[c]; a.v[c] = ta.v[c] + tv.v[c]; }
  }
  pf4(xout)[i] = o;
  pf4(tacc)[i] = a;
}

// aaug[b,l, t*D+d] = tacc[b, (l-1+t) mod L, d]   (circular)
__global__ __launch_bounds__(512) void build_aaug_kernel(
    const float* __restrict__ tacc, float* __restrict__ aaug)
{
  const int b = blockIdx.y, l = blockIdx.x, d = threadIdx.x;
  float* outp = aaug + ((size_t)b * LL + l) * (3 * DD);
  const float* tb = tacc + (size_t)b * LL * DD;
#pragma unroll
  for (int t = 0; t < 3; ++t) {
    int li = (l - 1 + t + LL) & (LL - 1);
    outp[t * DD + d] = tb[(size_t)li * DD + d];
  }
}

// ---------------------------------------------------------------------------
extern "C" void kernel_launch(void* const* d_in, const int* in_sizes, int n_in,
                              void* d_out, int out_size, void* d_ws, size_t ws_size,
                              hipStream_t stream)
{
  const float* x      = (const float*)d_in[0];
  const float* cross  = (const float*)d_in[1];
  const float* wq_s   = (const float*)d_in[2];
  const float* wk_s   = (const float*)d_in[3];
  const float* wv_s   = (const float*)d_in[4];
  const float* wo_s   = (const float*)d_in[5];
  const float* wq_c   = (const float*)d_in[6];
  const float* wk_c   = (const float*)d_in[7];
  const float* wv_c   = (const float*)d_in[8];
  const float* wo_c   = (const float*)d_in[9];
  const float* conv1  = (const float*)d_in[10];
  const float* conv2  = (const float*)d_in[11];
  const float* dw     = (const float*)d_in[12];
  const float* kp_w1  = (const float*)d_in[13];
  const float* kp_b1  = (const float*)d_in[14];
  const float* kp_w2  = (const float*)d_in[15];
  const float* kp_b2  = (const float*)d_in[16];
  const float* pw1    = (const float*)d_in[17];
  const float* pw2    = (const float*)d_in[18];
  const float* sscale = (const float*)d_in[19];
  const float* cscale = (const float*)d_in[20];

  float* out = (float*)d_out;
  float* ws  = (float*)d_ws;

  const size_t NBLD = (size_t)BB * LL * DD;   // 8,388,608 floats (32 MiB)
  float* xcur   = ws;                // persistent residual stream
  float* tacc   = ws + NBLD;         // persistent trend accumulator
  float* big    = ws + 2 * NBLD;     // 4*NBLD region, reused per phase
  float* qb     = big;
  float* kb     = big + NBLD;
  float* vb     = big + 2 * NBLD;
  float* attno  = big;               // attention O in-place over Q
  float* hidden = big;               // FFN hidden: exactly 4*NBLD
  float* aaug   = big;               // [B*L, 3D]: 3*NBLD
  float* hconv  = big + 3 * NBLD;
  float* trendb = big;               // trend scratch
  float* smallp = ws + 6 * NBLD;
  float* wT     = smallp;                    // B*KMAX*D = 819200
  int*   kvals  = (int*)(smallp + 819200);   // 32 ints (64 floats reserved)
  float* wbase  = smallp + 819200 + 64;
  // Split-bf16 weight buffers ([2][N][K] shorts == N*K floats each):
  short* w1r_sp = (short*)(wbase);                         // 512x1536: 786432 fl
  short* wsp[8];                                           // 8 attn weights
  for (int i = 0; i < 8; ++i) wsp[i] = (short*)(wbase + 786432 + (size_t)i * 262144);
  short* c1_sp  = (short*)(wbase + 786432 + 8 * 262144);             // 1048576 fl
  short* c2_sp  = (short*)(wbase + 786432 + 8 * 262144 + 1048576);   // 1048576 fl
  short* pw2_sp = (short*)(wbase + 786432 + 8 * 262144 + 2 * 1048576); // 262144 fl

  const int M = BB * LL;  // 16384
  const dim3 g512(4, 128), gFF1(16, 128), gBL(LL, BB), gSM(2, BB), gWT(16, 16);

  // ---- weight prep (split to bf16 hi/lo; transpose [K][N]->[N][K] where needed)
  conv_w_t_kernel<<<gWT,256,0,stream>>>(wq_s, wsp[0], DD, DD);
  conv_w_t_kernel<<<gWT,256,0,stream>>>(wk_s, wsp[1], DD, DD);
  conv_w_t_kernel<<<gWT,256,0,stream>>>(wv_s, wsp[2], DD, DD);
  conv_w_t_kernel<<<gWT,256,0,stream>>>(wo_s, wsp[3], DD, DD);
  conv_w_t_kernel<<<gWT,256,0,stream>>>(wq_c, wsp[4], DD, DD);
  conv_w_t_kernel<<<gWT,256,0,stream>>>(wk_c, wsp[5], DD, DD);
  conv_w_t_kernel<<<gWT,256,0,stream>>>(wv_c, wsp[6], DD, DD);
  conv_w_t_kernel<<<gWT,256,0,stream>>>(wo_c, wsp[7], DD, DD);
  conv_w_kernel<<<4096,256,0,stream>>>(conv1, c1_sp, (size_t)DFF * DD);
  conv_w_kernel<<<4096,256,0,stream>>>(conv2, c2_sp, (size_t)DD * DFF);
  conv_w_kernel<<<1024,256,0,stream>>>(pw2, pw2_sp, (size_t)DD * DD);
  rearrange_w1_bf_kernel<<<512,256,0,stream>>>(pw1, w1r_sp);

  // ---- self attention ----
  gemm_bf<false,false><<<g512,256,0,stream>>>(x, DD, wsp[0], qb, DD, nullptr, nullptr, M, DD, DD);
  gemm_bf<false,false><<<g512,256,0,stream>>>(x, DD, wsp[1], kb, DD, nullptr, nullptr, M, DD, DD);
  gemm_bf<false,false><<<g512,256,0,stream>>>(x, DD, wsp[2], vb, DD, nullptr, nullptr, M, DD, DD);
  attn_kernel<<<dim3(8, BB*HH),256,0,stream>>>(qb, kb, vb, attno);
  gemm_bf<false,true ><<<g512,256,0,stream>>>(attno, DD, wsp[3], xcur, DD, x, sscale, M, DD, DD);

  // ---- decomp 1 ----
  kp_head_kernel<<<BB,256,0,stream>>>(xcur, kp_w1, kp_b1, kp_w2, kp_b2, kvals);
  softmax_w_kernel<<<gSM,256,0,stream>>>(dw, kvals, wT);
  trend_kernel<<<gBL,512,0,stream>>>(xcur, wT, kvals, trendb);
  apply_kernel<<<8192,256,0,stream>>>(xcur, trendb, xcur, tacc, 1);

  // ---- cross attention ----
  gemm_bf<false,false><<<g512,256,0,stream>>>(xcur, DD, wsp[4], qb, DD, nullptr, nullptr, M, DD, DD);
  gemm_bf<false,false><<<g512,256,0,stream>>>(cross, DD, wsp[5], kb, DD, nullptr, nullptr, M, DD, DD);
  gemm_bf<false,false><<<g512,256,0,stream>>>(cross, DD, wsp[6], vb, DD, nullptr, nullptr, M, DD, DD);
  attn_kernel<<<dim3(8, BB*HH),256,0,stream>>>(qb, kb, vb, attno);
  gemm_bf<false,true ><<<g512,256,0,stream>>>(attno, DD, wsp[7], xcur, DD, xcur, cscale, M, DD, DD);

  // ---- decomp 2 ----
  kp_head_kernel<<<BB,256,0,stream>>>(xcur, kp_w1+131072, kp_b1+256, kp_w2+256, kp_b2+1, kvals);
  softmax_w_kernel<<<gSM,256,0,stream>>>(dw+25600, kvals, wT);
  trend_kernel<<<gBL,512,0,stream>>>(xcur, wT, kvals, trendb);
  apply_kernel<<<8192,256,0,stream>>>(xcur, trendb, xcur, tacc, 0);

  // ---- conv FFN ----
  gemm_bf<true ,false><<<gFF1,256,0,stream>>>(xcur, DD, c1_sp, hidden, DFF, nullptr, nullptr, M, DFF, DD);
  gemm_bf<false,true ><<<g512,256,0,stream>>>(hidden, DFF, c2_sp, xcur, DD, xcur, nullptr, M, DD, DFF);

  // ---- decomp 3 (x3 straight to d_out) ----
  kp_head_kernel<<<BB,256,0,stream>>>(xcur, kp_w1+262144, kp_b1+512, kp_w2+512, kp_b2+2, kvals);
  softmax_w_kernel<<<gSM,256,0,stream>>>(dw+51200, kvals, wT);
  trend_kernel<<<gBL,512,0,stream>>>(xcur, wT, kvals, trendb);
  apply_kernel<<<8192,256,0,stream>>>(xcur, trendb, out, tacc, 0);

  // ---- trend projection ----
  build_aaug_kernel<<<gBL,512,0,stream>>>(tacc, aaug);
  gemm_bf<true ,false><<<g512,256,0,stream>>>(aaug, 3*DD, w1r_sp, hconv, DD, nullptr, nullptr, M, DD, 3*DD);
  gemm_bf<false,false><<<g512,256,0,stream>>>(hconv, DD, pw2_sp, out+NBLD, DD, nullptr, nullptr, M, DD, DD);
}

// Round 9
// 1775.829 us; speedup vs baseline: 2.0231x; 1.2554x over previous
//
#include <hip/hip_runtime.h>
#include <hip/hip_bf16.h>
#include <cmath>
#include <cstdint>

// Problem constants
#define BB   32
#define LL   512
#define DD   512
#define HH   8
#define DHH  64
#define DFF  2048
#define KMAXC 50

struct __align__(16) F4 { float v[4]; };
static __device__ __forceinline__ const F4* cf4(const float* p) { return reinterpret_cast<const F4*>(p); }
static __device__ __forceinline__ F4*       pf4(float* p)       { return reinterpret_cast<F4*>(p); }

typedef __attribute__((ext_vector_type(8))) short short8;   // 8 bf16 = 4 VGPR (MFMA frag)
typedef __attribute__((ext_vector_type(4))) short short4v;  // 4 bf16 (b64)
typedef __attribute__((ext_vector_type(4))) float f32x4;    // MFMA accumulator

// fp32 -> bf16 round-to-nearest-even (bit trick), and back (exact)
static __device__ __forceinline__ ushort f2bf(float f) {
  unsigned u = __float_as_uint(f);
  return (ushort)((u + 0x7FFFu + ((u >> 16) & 1u)) >> 16);
}
static __device__ __forceinline__ float bf2f(ushort h) {
  return __uint_as_float(((unsigned)h) << 16);
}

// ---------------------------------------------------------------------------
// Split-bf16 MFMA GEMM (HW-validated r8: 3.59->2.23ms, absmax unchanged).
// C[M,N] = A[M,K] (fp32) * W, W pre-split bf16 planes [2][N][K] (hi, lo).
// ---------------------------------------------------------------------------
template<bool RELU, bool RES>
__global__ __launch_bounds__(256) void gemm_bf(
    const float* __restrict__ A, int lda,
    const short* __restrict__ W,          // [2][N][K] bf16 planes
    float* __restrict__ C, int ldc,
    const float* __restrict__ res, const float* __restrict__ scale_ptr,
    int M, int N, int K)
{
  const int tid = threadIdx.x;
  const int n0 = blockIdx.x * 128, m0 = blockIdx.y * 128;

  __shared__ short As[2][128][40];   // [hi/lo][m][k] padded
  __shared__ short Bs[2][128][40];   // [hi/lo][n][k] padded

  const int lane = tid & 63;
  const int wid  = tid >> 6;
  const int wr   = (wid >> 1) * 64;      // wave quadrant row
  const int wc   = (wid & 1) * 64;       // wave quadrant col
  const int fr   = lane & 15;            // row/col within 16x16 tile
  const int fkb  = (lane >> 4) * 8;      // k fragment offset (shorts)

  f32x4 acc[4][4] = {};

  const int srow = tid >> 1;             // 0..127 (m-row or n-row)
  const int skh  = (tid & 1) << 4;       // 0 or 16 (k half)

  const size_t wplane = (size_t)N * K;   // lo-plane offset in shorts

  for (int k0 = 0; k0 < K; k0 += 32) {
    { // stage A (fp32 -> hi/lo bf16)
      const float* ap = A + (size_t)(m0 + srow) * lda + (k0 + skh);
#pragma unroll
      for (int q = 0; q < 2; ++q) {
        F4 va = cf4(ap)[2 * q];
        F4 vb = cf4(ap)[2 * q + 1];
        short8 hh, ll;
#pragma unroll
        for (int e = 0; e < 4; ++e) {
          ushort h0 = f2bf(va.v[e]);
          hh[e]     = (short)h0;
          ll[e]     = (short)f2bf(va.v[e] - bf2f(h0));
          ushort h1 = f2bf(vb.v[e]);
          hh[4 + e] = (short)h1;
          ll[4 + e] = (short)f2bf(vb.v[e] - bf2f(h1));
        }
        *(short8*)&As[0][srow][skh + q * 8] = hh;
        *(short8*)&As[1][srow][skh + q * 8] = ll;
      }
    }
    { // stage W (already bf16 split)
      const short* wp = W + (size_t)(n0 + srow) * K + (k0 + skh);
      *(short8*)&Bs[0][srow][skh]     = *(const short8*)wp;
      *(short8*)&Bs[0][srow][skh + 8] = *(const short8*)(wp + 8);
      *(short8*)&Bs[1][srow][skh]     = *(const short8*)(wp + wplane);
      *(short8*)&Bs[1][srow][skh + 8] = *(const short8*)(wp + wplane + 8);
    }
    __syncthreads();

    short8 bhi[4], blo[4];
#pragma unroll
    for (int j = 0; j < 4; ++j) {
      bhi[j] = *(const short8*)&Bs[0][wc + j * 16 + fr][fkb];
      blo[j] = *(const short8*)&Bs[1][wc + j * 16 + fr][fkb];
    }
#pragma unroll
    for (int i = 0; i < 4; ++i) {
      short8 ahi = *(const short8*)&As[0][wr + i * 16 + fr][fkb];
      short8 alo = *(const short8*)&As[1][wr + i * 16 + fr][fkb];
#pragma unroll
      for (int j = 0; j < 4; ++j) {
        acc[i][j] = __builtin_amdgcn_mfma_f32_16x16x32_bf16(alo, bhi[j], acc[i][j], 0, 0, 0);
        acc[i][j] = __builtin_amdgcn_mfma_f32_16x16x32_bf16(ahi, blo[j], acc[i][j], 0, 0, 0);
        acc[i][j] = __builtin_amdgcn_mfma_f32_16x16x32_bf16(ahi, bhi[j], acc[i][j], 0, 0, 0);
      }
    }
    __syncthreads();
  }

  float scl = 1.0f;
  if (RES) scl = scale_ptr ? *scale_ptr : 1.0f;
  const int er = (lane >> 4) << 2;       // 0,4,8,12
#pragma unroll
  for (int i = 0; i < 4; ++i) {
#pragma unroll
    for (int p = 0; p < 4; ++p) {
      const size_t row = (size_t)(m0 + wr + i * 16 + er + p);
#pragma unroll
      for (int j = 0; j < 4; ++j) {
        const int col = n0 + wc + j * 16 + fr;
        float v = acc[i][j][p];
        if (RELU) v = fmaxf(v, 0.0f);
        if (RES)  v = fmaf(v, scl, res[row * (size_t)ldc + col]);
        C[row * (size_t)ldc + col] = v;
      }
    }
  }
}

// ---------------------------------------------------------------------------
// Weight prep kernels (unchanged from r8, HW-validated)
// ---------------------------------------------------------------------------
__global__ __launch_bounds__(256) void conv_w_t_kernel(
    const float* __restrict__ W, short* __restrict__ out, int K, int N)
{
  __shared__ float t[32][33];
  const int k0 = blockIdx.x * 32, n0 = blockIdx.y * 32;
  const int tx = threadIdx.x & 31, ty = threadIdx.x >> 5;   // 32 x 8
  for (int r = ty; r < 32; r += 8)
    t[r][tx] = W[(size_t)(k0 + r) * N + n0 + tx];
  __syncthreads();
  const size_t plane = (size_t)N * K;
  for (int r = ty; r < 32; r += 8) {
    float f = t[tx][r];                       // W[k0+tx][n0+r]
    ushort h = f2bf(f);
    out[(size_t)(n0 + r) * K + k0 + tx]         = (short)h;
    out[plane + (size_t)(n0 + r) * K + k0 + tx] = (short)f2bf(f - bf2f(h));
  }
}

__global__ __launch_bounds__(256) void conv_w_kernel(
    const float* __restrict__ W, short* __restrict__ out, size_t NK)
{
  size_t i = (size_t)blockIdx.x * 256 + threadIdx.x;
  float f = W[i];
  ushort h = f2bf(f);
  out[i]      = (short)h;
  out[NK + i] = (short)f2bf(f - bf2f(h));
}

__global__ __launch_bounds__(256) void rearrange_w1_bf_kernel(
    const float* __restrict__ pw1, short* __restrict__ out)
{
  const int o = blockIdx.x;
  const size_t plane = (size_t)DD * (3 * DD);
  for (int i = threadIdx.x; i < 3 * DD; i += 256) {
    int t = i / DD, d = i - t * DD;
    float f = pw1[(size_t)o * (3 * DD) + d * 3 + t];
    ushort h = f2bf(f);
    out[(size_t)o * (3 * DD) + i]         = (short)h;
    out[plane + (size_t)o * (3 * DD) + i] = (short)f2bf(f - bf2f(h));
  }
}

// ---------------------------------------------------------------------------
// MFMA flash attention (bf16 operands, fp32 accumulate), dh=64, L=512.
// Block: 256 thr = 4 waves, 64 q-rows (16/wave); K-tiles of 32.
// grid = (L/64, B*H).  O may alias Q (Q staged to LDS first; disjoint slices).
//
// Swapped QK^T: S^T = mfma(A=Kfrag, B=Qfrag) -> C[m=kcol][n=q]; both operands
// read naturally from row-major [row][d] bf16 LDS (layout HW-validated by
// gemm_bf r8).  Softmax per q = lane&15: butterfly shfl_xor(16,32) over the
// 4 lanes sharing q.  P packed bf16 -> per-wave LDS [q][k] (C-layout regs are
// 4 consecutive k -> b64 writes), read back as natural A-frag.
// PV: O[q][d] = mfma(A=P[q][k], B=Vt[d][k]); V staged TRANSPOSED with a
// conflict-free mapping (2 k-cols/thread -> b32 writes, bank=16(dq&1)+kp).
// alpha/1-l cross C-layout (q=4*fg+reg) via 16-float LDS rows read as F4.
// ---------------------------------------------------------------------------
__global__ __launch_bounds__(256) void attn_mfma_kernel(
    const float* __restrict__ Q, const float* __restrict__ K,
    const float* __restrict__ V, float* __restrict__ O)
{
  const int bh = blockIdx.y;
  const int b = bh >> 3, h = bh & 7;
  const int q0 = blockIdx.x * 64;
  const int tid = threadIdx.x;
  const int wid  = tid >> 6;        // wave id: q-rows [wid*16, wid*16+16)
  const int lane = tid & 63;
  const int fr = lane & 15;         // frag row index
  const int fg = lane >> 4;         // frag k-group

  __shared__ short Qs[64][72];      // bf16 [q][d]
  __shared__ short Ks[32][72];      // bf16 [kcol][d]
  __shared__ short Vt[64][40];      // bf16 [d][k]  (V transposed)
  __shared__ short Ps[4][16][40];   // per-wave P [q][k]
  __shared__ __align__(16) float Al[4][16];   // per-wave alpha[q]
  __shared__ __align__(16) float Ll[4][16];   // per-wave 1/l[q]

  const size_t base = ((size_t)b * LL) * DD + (size_t)h * DHH;

  // ---- stage Q (scale 1/8 folded in), fp32 -> bf16 ----
  {
    const int row = tid >> 2, dc = (tid & 3) << 4;
    const float* qp = &Q[base + (size_t)(q0 + row) * DD + dc];
#pragma unroll
    for (int hf = 0; hf < 2; ++hf) {
      F4 a = cf4(qp)[2 * hf], c = cf4(qp)[2 * hf + 1];
      short8 s8;
#pragma unroll
      for (int e = 0; e < 4; ++e) {
        s8[e]     = (short)f2bf(a.v[e] * 0.125f);
        s8[4 + e] = (short)f2bf(c.v[e] * 0.125f);
      }
      *(short8*)&Qs[row][dc + hf * 8] = s8;
    }
  }
  __syncthreads();

  // Q fragments are invariant over the K loop: hoist.
  const short8 qf0 = *(const short8*)&Qs[wid * 16 + fr][fg * 8];
  const short8 qf1 = *(const short8*)&Qs[wid * 16 + fr][32 + fg * 8];

  float mrow = -1e30f, lrow = 0.0f;   // softmax state for q = fr (dup over fg)
  f32x4 oacc[4] = {};                 // O[q=4*fg+r][d = dt*16 + fr]

  for (int kt = 0; kt < 16; ++kt) {
    const int kbase = kt * 32;
    // ---- stage K tile bf16 [32][64] ----
    {
      const int row = tid >> 3, dc = (tid & 7) << 3;
      const float* kp = &K[base + (size_t)(kbase + row) * DD + dc];
      F4 a = cf4(kp)[0], c = cf4(kp)[1];
      short8 s8;
#pragma unroll
      for (int e = 0; e < 4; ++e) {
        s8[e]     = (short)f2bf(a.v[e]);
        s8[4 + e] = (short)f2bf(c.v[e]);
      }
      *(short8*)&Ks[row][dc] = s8;
    }
    // ---- stage V transposed: thread owns 2 k-cols x 4 d-rows ----
    {
      const int kp2 = (tid & 15) * 2, dq = tid >> 4;   // d = dq*4
      const float* vp0 = &V[base + (size_t)(kbase + kp2) * DD + dq * 4];
      const float* vp1 = vp0 + DD;
      F4 a = *cf4(vp0), c = *cf4(vp1);
#pragma unroll
      for (int e = 0; e < 4; ++e) {
        unsigned pk = (unsigned)f2bf(a.v[e]) | ((unsigned)f2bf(c.v[e]) << 16);
        *(unsigned*)&Vt[dq * 4 + e][kp2] = pk;
      }
    }
    __syncthreads();

    // ---- S^T tiles: C[m=kcol][n=q], contraction over d (2 steps) ----
    f32x4 st0 = {}, st1 = {};
    {
      short8 kf;
      kf  = *(const short8*)&Ks[fr][fg * 8];
      st0 = __builtin_amdgcn_mfma_f32_16x16x32_bf16(kf, qf0, st0, 0, 0, 0);
      kf  = *(const short8*)&Ks[fr][32 + fg * 8];
      st0 = __builtin_amdgcn_mfma_f32_16x16x32_bf16(kf, qf1, st0, 0, 0, 0);
      kf  = *(const short8*)&Ks[16 + fr][fg * 8];
      st1 = __builtin_amdgcn_mfma_f32_16x16x32_bf16(kf, qf0, st1, 0, 0, 0);
      kf  = *(const short8*)&Ks[16 + fr][32 + fg * 8];
      st1 = __builtin_amdgcn_mfma_f32_16x16x32_bf16(kf, qf1, st1, 0, 0, 0);
    }

    // ---- online softmax for q = fr; 8 scores/lane ----
    float pmax = st0[0];
#pragma unroll
    for (int r = 1; r < 4; ++r) pmax = fmaxf(pmax, st0[r]);
#pragma unroll
    for (int r = 0; r < 4; ++r) pmax = fmaxf(pmax, st1[r]);
    pmax = fmaxf(pmax, __shfl_xor(pmax, 16));
    pmax = fmaxf(pmax, __shfl_xor(pmax, 32));
    const float mnew  = fmaxf(mrow, pmax);
    const float alpha = __expf(mrow - mnew);
    float p[8], psum = 0.0f;
#pragma unroll
    for (int r = 0; r < 4; ++r) { p[r]     = __expf(st0[r] - mnew); psum += p[r]; }
#pragma unroll
    for (int r = 0; r < 4; ++r) { p[4 + r] = __expf(st1[r] - mnew); psum += p[4 + r]; }
    psum += __shfl_xor(psum, 16);
    psum += __shfl_xor(psum, 32);
    lrow = lrow * alpha + psum;
    mrow = mnew;

    // ---- P -> LDS (bf16): lane holds kcols {4fg+r} and {16+4fg+r} for q=fr
    {
      short4v pk0, pk1;
#pragma unroll
      for (int r = 0; r < 4; ++r) {
        pk0[r] = (short)f2bf(p[r]);
        pk1[r] = (short)f2bf(p[4 + r]);
      }
      *(short4v*)&Ps[wid][fr][4 * fg]      = pk0;
      *(short4v*)&Ps[wid][fr][16 + 4 * fg] = pk1;
    }
    if (fg == 0) Al[wid][fr] = alpha;
    __syncthreads();

    // ---- rescale O, then PV: O[q][d] += P[q][k] * V[k][d] ----
    {
      F4 av = *cf4(&Al[wid][fg * 4]);     // alpha for rows q = 4fg+r
#pragma unroll
      for (int dt = 0; dt < 4; ++dt)
#pragma unroll
        for (int r = 0; r < 4; ++r) oacc[dt][r] *= av.v[r];

      short8 pf = *(const short8*)&Ps[wid][fr][fg * 8];
#pragma unroll
      for (int dt = 0; dt < 4; ++dt) {
        short8 vf = *(const short8*)&Vt[dt * 16 + fr][fg * 8];
        oacc[dt] = __builtin_amdgcn_mfma_f32_16x16x32_bf16(pf, vf, oacc[dt], 0, 0, 0);
      }
    }
    __syncthreads();   // before restaging K/Vt
  }

  // ---- epilogue: scale by 1/l (cross lane-layout via LDS) ----
  if (fg == 0) Ll[wid][fr] = 1.0f / lrow;
  __syncthreads();
  F4 lv = *cf4(&Ll[wid][fg * 4]);
#pragma unroll
  for (int r = 0; r < 4; ++r) {
    const size_t row = (size_t)(q0 + wid * 16 + 4 * fg + r);
#pragma unroll
    for (int dt = 0; dt < 4; ++dt)
      O[base + row * DD + dt * 16 + fr] = oacc[dt][r] * lv.v[r];
  }
}

// ---------------------------------------------------------------------------
// Kernel-size predictor head. One block per sample.
// ---------------------------------------------------------------------------
__global__ __launch_bounds__(256) void kp_head_kernel(
    const float* __restrict__ x, const float* __restrict__ w1,
    const float* __restrict__ b1, const float* __restrict__ w2,
    const float* __restrict__ b2, int* __restrict__ kout)
{
  const int b = blockIdx.x, tid = threadIdx.x;
  __shared__ float xg[DD];
  __shared__ float h1s[256];
  __shared__ float red[256];
  const float* xb = x + (size_t)b * LL * DD;

  for (int d = tid; d < DD; d += 256) {
    float s = 0.0f;
    for (int l = 0; l < LL; ++l) s += xb[(size_t)l * DD + d];
    xg[d] = s * (1.0f / (float)LL);
  }
  __syncthreads();
  {
    float s = b1[tid];
    for (int d = 0; d < DD; ++d) s = fmaf(xg[d], w1[d * 256 + tid], s);
    h1s[tid] = fmaxf(s, 0.0f);
  }
  __syncthreads();
  red[tid] = h1s[tid] * w2[tid];
  __syncthreads();
  for (int st = 128; st > 0; st >>= 1) {
    if (tid < st) red[tid] += red[tid + st];
    __syncthreads();
  }
  if (tid == 0) {
    float z = red[0] + b2[0];
    float kf = 45.0f / (1.0f + expf(-z)) + 5.0f;
    int k = (int)rintf(kf);          // round-half-to-even, matches jnp.round
    if (k > 50) k = 50;
    if (k < 3) k = 3;
    if ((k & 1) == 0) k -= 1;
    if (k < 3) k = 3;
    kout[b] = k;
  }
}

// Per (b,d) softmax over first k taps of dw[d,:]; store transposed [B][KMAX][D]
__global__ __launch_bounds__(256) void softmax_w_kernel(
    const float* __restrict__ dw, const int* __restrict__ kvals,
    float* __restrict__ wT)
{
  const int b = blockIdx.y;
  const int d = blockIdx.x * 256 + threadIdx.x;
  const int k = kvals[b];
  const float* row = dw + (size_t)d * KMAXC;
  float mx = -1e30f;
  for (int j = 0; j < k; ++j) mx = fmaxf(mx, row[j]);
  float ssum = 0.0f;
  for (int j = 0; j < k; ++j) ssum += __expf(row[j] - mx);
  float inv = 1.0f / ssum;
  float* w = wT + (size_t)b * KMAXC * DD + d;
  for (int j = 0; j < k; ++j) w[(size_t)j * DD] = __expf(row[j] - mx) * inv;
}

// trend[b,l,d] = sum_{j<k} wT[b,j,d] * x[b, clamp(l-half+j), d]
__global__ __launch_bounds__(512) void trend_kernel(
    const float* __restrict__ xin, const float* __restrict__ wT,
    const int* __restrict__ kvals, float* __restrict__ tr)
{
  const int b = blockIdx.y, l = blockIdx.x, d = threadIdx.x;
  const int k = kvals[b], half = k >> 1;
  const float* xb = xin + (size_t)b * LL * DD;
  const float* w = wT + (size_t)b * KMAXC * DD + d;
  float t = 0.0f;
  for (int j = 0; j < k; ++j) {
    int li = l - half + j;
    li = li < 0 ? 0 : (li > LL - 1 ? LL - 1 : li);
    t = fmaf(w[(size_t)j * DD], xb[(size_t)li * DD + d], t);
  }
  tr[((size_t)b * LL + l) * DD + d] = t;
}

// xout = xin - tr;  tacc = (first ? tr : tacc + tr)
__global__ __launch_bounds__(256) void apply_kernel(
    const float* __restrict__ xin, const float* __restrict__ tr,
    float* __restrict__ xout, float* __restrict__ tacc, int first)
{
  size_t i = (size_t)blockIdx.x * blockDim.x + threadIdx.x; // F4 idx
  F4 xv = cf4(xin)[i];
  F4 tv = cf4(tr)[i];
  F4 o, a;
  if (first) {
#pragma unroll
    for (int c = 0; c < 4; ++c) { o.v[c] = xv.v[c] - tv.v[c]; a.v[c] = tv.v[c]; }
  } else {
    F4 ta = cf4((const float*)tacc)[i];
#pragma unroll
    for (int c = 0; c < 4; ++c) { o.v[c] = xv.v[c] - tv.v[c]; a.v[c] = ta.v[c] + tv.v[c]; }
  }
  pf4(xout)[i] = o;
  pf4(tacc)[i] = a;
}

// aaug[b,l, t*D+d] = tacc[b, (l-1+t) mod L, d]   (circular)
__global__ __launch_bounds__(512) void build_aaug_kernel(
    const float* __restrict__ tacc, float* __restrict__ aaug)
{
  const int b = blockIdx.y, l = blockIdx.x, d = threadIdx.x;
  float* outp = aaug + ((size_t)b * LL + l) * (3 * DD);
  const float* tb = tacc + (size_t)b * LL * DD;
#pragma unroll
  for (int t = 0; t < 3; ++t) {
    int li = (l - 1 + t + LL) & (LL - 1);
    outp[t * DD + d] = tb[(size_t)li * DD + d];
  }
}

// ---------------------------------------------------------------------------
extern "C" void kernel_launch(void* const* d_in, const int* in_sizes, int n_in,
                              void* d_out, int out_size, void* d_ws, size_t ws_size,
                              hipStream_t stream)
{
  const float* x      = (const float*)d_in[0];
  const float* cross  = (const float*)d_in[1];
  const float* wq_s   = (const float*)d_in[2];
  const float* wk_s   = (const float*)d_in[3];
  const float* wv_s   = (const float*)d_in[4];
  const float* wo_s   = (const float*)d_in[5];
  const float* wq_c   = (const float*)d_in[6];
  const float* wk_c   = (const float*)d_in[7];
  const float* wv_c   = (const float*)d_in[8];
  const float* wo_c   = (const float*)d_in[9];
  const float* conv1  = (const float*)d_in[10];
  const float* conv2  = (const float*)d_in[11];
  const float* dw     = (const float*)d_in[12];
  const float* kp_w1  = (const float*)d_in[13];
  const float* kp_b1  = (const float*)d_in[14];
  const float* kp_w2  = (const float*)d_in[15];
  const float* kp_b2  = (const float*)d_in[16];
  const float* pw1    = (const float*)d_in[17];
  const float* pw2    = (const float*)d_in[18];
  const float* sscale = (const float*)d_in[19];
  const float* cscale = (const float*)d_in[20];

  float* out = (float*)d_out;
  float* ws  = (float*)d_ws;

  const size_t NBLD = (size_t)BB * LL * DD;   // 8,388,608 floats (32 MiB)
  float* xcur   = ws;                // persistent residual stream
  float* tacc   = ws + NBLD;         // persistent trend accumulator
  float* big    = ws + 2 * NBLD;     // 4*NBLD region, reused per phase
  float* qb     = big;
  float* kb     = big + NBLD;
  float* vb     = big + 2 * NBLD;
  float* attno  = big;               // attention O in-place over Q
  float* hidden = big;               // FFN hidden: exactly 4*NBLD
  float* aaug   = big;               // [B*L, 3D]: 3*NBLD
  float* hconv  = big + 3 * NBLD;
  float* trendb = big;               // trend scratch
  float* smallp = ws + 6 * NBLD;
  float* wT     = smallp;                    // B*KMAX*D = 819200
  int*   kvals  = (int*)(smallp + 819200);   // 32 ints (64 floats reserved)
  float* wbase  = smallp + 819200 + 64;
  // Split-bf16 weight buffers ([2][N][K] shorts == N*K floats each):
  short* w1r_sp = (short*)(wbase);                         // 512x1536: 786432 fl
  short* wsp[8];                                           // 8 attn weights
  for (int i = 0; i < 8; ++i) wsp[i] = (short*)(wbase + 786432 + (size_t)i * 262144);
  short* c1_sp  = (short*)(wbase + 786432 + 8 * 262144);             // 1048576 fl
  short* c2_sp  = (short*)(wbase + 786432 + 8 * 262144 + 1048576);   // 1048576 fl
  short* pw2_sp = (short*)(wbase + 786432 + 8 * 262144 + 2 * 1048576); // 262144 fl

  const int M = BB * LL;  // 16384
  const dim3 g512(4, 128), gFF1(16, 128), gBL(LL, BB), gSM(2, BB), gWT(16, 16);

  // ---- weight prep ----
  conv_w_t_kernel<<<gWT,256,0,stream>>>(wq_s, wsp[0], DD, DD);
  conv_w_t_kernel<<<gWT,256,0,stream>>>(wk_s, wsp[1], DD, DD);
  conv_w_t_kernel<<<gWT,256,0,stream>>>(wv_s, wsp[2], DD, DD);
  conv_w_t_kernel<<<gWT,256,0,stream>>>(wo_s, wsp[3], DD, DD);
  conv_w_t_kernel<<<gWT,256,0,stream>>>(wq_c, wsp[4], DD, DD);
  conv_w_t_kernel<<<gWT,256,0,stream>>>(wk_c, wsp[5], DD, DD);
  conv_w_t_kernel<<<gWT,256,0,stream>>>(wv_c, wsp[6], DD, DD);
  conv_w_t_kernel<<<gWT,256,0,stream>>>(wo_c, wsp[7], DD, DD);
  conv_w_kernel<<<4096,256,0,stream>>>(conv1, c1_sp, (size_t)DFF * DD);
  conv_w_kernel<<<4096,256,0,stream>>>(conv2, c2_sp, (size_t)DD * DFF);
  conv_w_kernel<<<1024,256,0,stream>>>(pw2, pw2_sp, (size_t)DD * DD);
  rearrange_w1_bf_kernel<<<512,256,0,stream>>>(pw1, w1r_sp);

  // ---- self attention ----
  gemm_bf<false,false><<<g512,256,0,stream>>>(x, DD, wsp[0], qb, DD, nullptr, nullptr, M, DD, DD);
  gemm_bf<false,false><<<g512,256,0,stream>>>(x, DD, wsp[1], kb, DD, nullptr, nullptr, M, DD, DD);
  gemm_bf<false,false><<<g512,256,0,stream>>>(x, DD, wsp[2], vb, DD, nullptr, nullptr, M, DD, DD);
  attn_mfma_kernel<<<dim3(8, BB*HH),256,0,stream>>>(qb, kb, vb, attno);
  gemm_bf<false,true ><<<g512,256,0,stream>>>(attno, DD, wsp[3], xcur, DD, x, sscale, M, DD, DD);

  // ---- decomp 1 ----
  kp_head_kernel<<<BB,256,0,stream>>>(xcur, kp_w1, kp_b1, kp_w2, kp_b2, kvals);
  softmax_w_kernel<<<gSM,256,0,stream>>>(dw, kvals, wT);
  trend_kernel<<<gBL,512,0,stream>>>(xcur, wT, kvals, trendb);
  apply_kernel<<<8192,256,0,stream>>>(xcur, trendb, xcur, tacc, 1);

  // ---- cross attention ----
  gemm_bf<false,false><<<g512,256,0,stream>>>(xcur, DD, wsp[4], qb, DD, nullptr, nullptr, M, DD, DD);
  gemm_bf<false,false><<<g512,256,0,stream>>>(cross, DD, wsp[5], kb, DD, nullptr, nullptr, M, DD, DD);
  gemm_bf<false,false><<<g512,256,0,stream>>>(cross, DD, wsp[6], vb, DD, nullptr, nullptr, M, DD, DD);
  attn_mfma_kernel<<<dim3(8, BB*HH),256,0,stream>>>(qb, kb, vb, attno);
  gemm_bf<false,true ><<<g512,256,0,stream>>>(attno, DD, wsp[7], xcur, DD, xcur, cscale, M, DD, DD);

  // ---- decomp 2 ----
  kp_head_kernel<<<BB,256,0,stream>>>(xcur, kp_w1+131072, kp_b1+256, kp_w2+256, kp_b2+1, kvals);
  softmax_w_kernel<<<gSM,256,0,stream>>>(dw+25600, kvals, wT);
  trend_kernel<<<gBL,512,0,stream>>>(xcur, wT, kvals, trendb);
  apply_kernel<<<8192,256,0,stream>>>(xcur, trendb, xcur, tacc, 0);

  // ---- conv FFN ----
  gemm_bf<true ,false><<<gFF1,256,0,stream>>>(xcur, DD, c1_sp, hidden, DFF, nullptr, nullptr, M, DFF, DD);
  gemm_bf<false,true ><<<g512,256,0,stream>>>(hidden, DFF, c2_sp, xcur, DD, xcur, nullptr, M, DD, DFF);

  // ---- decomp 3 (x3 straight to d_out) ----
  kp_head_kernel<<<BB,256,0,stream>>>(xcur, kp_w1+262144, kp_b1+512, kp_w2+512, kp_b2+2, kvals);
  softmax_w_kernel<<<gSM,256,0,stream>>>(dw+51200, kvals, wT);
  trend_kernel<<<gBL,512,0,stream>>>(xcur, wT, kvals, trendb);
  apply_kernel<<<8192,256,0,stream>>>(xcur, trendb, out, tacc, 0);

  // ---- trend projection ----
  build_aaug_kernel<<<gBL,512,0,stream>>>(tacc, aaug);
  gemm_bf<true ,false><<<g512,256,0,stream>>>(aaug, 3*DD, w1r_sp, hconv, DD, nullptr, nullptr, M, DD, 3*DD);
  gemm_bf<false,false><<<g512,256,0,stream>>>(hconv, DD, pw2_sp, out+NBLD, DD, nullptr, nullptr, M, DD, DD);
}

// Round 10
// 1716.212 us; speedup vs baseline: 2.0934x; 1.0347x over previous
//
#include <hip/hip_runtime.h>
#include <hip/hip_bf16.h>
#include <cmath>
#include <cstdint>

// Problem constants
#define BB   32
#define LL   512
#define DD   512
#define HH   8
#define DHH  64
#define DFF  2048
#define KMAXC 50

struct __align__(16) F4 { float v[4]; };
static __device__ __forceinline__ const F4* cf4(const float* p) { return reinterpret_cast<const F4*>(p); }
static __device__ __forceinline__ F4*       pf4(float* p)       { return reinterpret_cast<F4*>(p); }

typedef __attribute__((ext_vector_type(8))) short short8;   // 8 bf16 = 4 VGPR (MFMA frag)
typedef __attribute__((ext_vector_type(4))) short short4v;  // 4 bf16 (b64)
typedef __attribute__((ext_vector_type(4))) float f32x4;    // MFMA accumulator

// fp32 -> bf16 round-to-nearest-even (bit trick), and back (exact)
static __device__ __forceinline__ ushort f2bf(float f) {
  unsigned u = __float_as_uint(f);
  return (ushort)((u + 0x7FFFu + ((u >> 16) & 1u)) >> 16);
}
static __device__ __forceinline__ float bf2f(ushort h) {
  return __uint_as_float(((unsigned)h) << 16);
}

// Bijective XCD-aware block swizzle (m204): XCD j processes a CONTIGUOUS
// chunk of original block ids, so blocks sharing an A-tile (consecutive ids,
// x-fastest) land on the SAME XCD and share its L2.  r9 PMC showed the
// square GEMMs at FETCH=283MB == zero-reuse bound (A-tile sharers split
// across 4 XCDs); this restores the sharing.
static __device__ __forceinline__ int xcd_swizzle(int b, int nwg) {
  const int xcd = b & 7, off = b >> 3;
  const int q = nwg >> 3, r = nwg & 7;
  return (xcd < r ? xcd * (q + 1) : r * (q + 1) + (xcd - r) * q) + off;
}

// ---------------------------------------------------------------------------
// Split-bf16 MFMA GEMM (HW-validated r8: 3.59->2.23ms, absmax unchanged).
// C[M,N] = A[M,K] (fp32) * W, W pre-split bf16 planes [2][N][K] (hi, lo).
// ---------------------------------------------------------------------------
template<bool RELU, bool RES>
__global__ __launch_bounds__(256) void gemm_bf(
    const float* __restrict__ A, int lda,
    const short* __restrict__ W,          // [2][N][K] bf16 planes
    float* __restrict__ C, int ldc,
    const float* __restrict__ res, const float* __restrict__ scale_ptr,
    int M, int N, int K)
{
  const int tid = threadIdx.x;
  int bswz = xcd_swizzle(blockIdx.y * gridDim.x + blockIdx.x,
                         gridDim.x * gridDim.y);
  const int n0 = (bswz % gridDim.x) * 128;
  const int m0 = (bswz / gridDim.x) * 128;

  __shared__ short As[2][128][40];   // [hi/lo][m][k] padded
  __shared__ short Bs[2][128][40];   // [hi/lo][n][k] padded

  const int lane = tid & 63;
  const int wid  = tid >> 6;
  const int wr   = (wid >> 1) * 64;      // wave quadrant row
  const int wc   = (wid & 1) * 64;       // wave quadrant col
  const int fr   = lane & 15;            // row/col within 16x16 tile
  const int fkb  = (lane >> 4) * 8;      // k fragment offset (shorts)

  f32x4 acc[4][4] = {};

  const int srow = tid >> 1;             // 0..127 (m-row or n-row)
  const int skh  = (tid & 1) << 4;       // 0 or 16 (k half)

  const size_t wplane = (size_t)N * K;   // lo-plane offset in shorts

  for (int k0 = 0; k0 < K; k0 += 32) {
    { // stage A (fp32 -> hi/lo bf16)
      const float* ap = A + (size_t)(m0 + srow) * lda + (k0 + skh);
#pragma unroll
      for (int q = 0; q < 2; ++q) {
        F4 va = cf4(ap)[2 * q];
        F4 vb = cf4(ap)[2 * q + 1];
        short8 hh, ll;
#pragma unroll
        for (int e = 0; e < 4; ++e) {
          ushort h0 = f2bf(va.v[e]);
          hh[e]     = (short)h0;
          ll[e]     = (short)f2bf(va.v[e] - bf2f(h0));
          ushort h1 = f2bf(vb.v[e]);
          hh[4 + e] = (short)h1;
          ll[4 + e] = (short)f2bf(vb.v[e] - bf2f(h1));
        }
        *(short8*)&As[0][srow][skh + q * 8] = hh;
        *(short8*)&As[1][srow][skh + q * 8] = ll;
      }
    }
    { // stage W (already bf16 split)
      const short* wp = W + (size_t)(n0 + srow) * K + (k0 + skh);
      *(short8*)&Bs[0][srow][skh]     = *(const short8*)wp;
      *(short8*)&Bs[0][srow][skh + 8] = *(const short8*)(wp + 8);
      *(short8*)&Bs[1][srow][skh]     = *(const short8*)(wp + wplane);
      *(short8*)&Bs[1][srow][skh + 8] = *(const short8*)(wp + wplane + 8);
    }
    __syncthreads();

    short8 bhi[4], blo[4];
#pragma unroll
    for (int j = 0; j < 4; ++j) {
      bhi[j] = *(const short8*)&Bs[0][wc + j * 16 + fr][fkb];
      blo[j] = *(const short8*)&Bs[1][wc + j * 16 + fr][fkb];
    }
#pragma unroll
    for (int i = 0; i < 4; ++i) {
      short8 ahi = *(const short8*)&As[0][wr + i * 16 + fr][fkb];
      short8 alo = *(const short8*)&As[1][wr + i * 16 + fr][fkb];
#pragma unroll
      for (int j = 0; j < 4; ++j) {
        acc[i][j] = __builtin_amdgcn_mfma_f32_16x16x32_bf16(alo, bhi[j], acc[i][j], 0, 0, 0);
        acc[i][j] = __builtin_amdgcn_mfma_f32_16x16x32_bf16(ahi, blo[j], acc[i][j], 0, 0, 0);
        acc[i][j] = __builtin_amdgcn_mfma_f32_16x16x32_bf16(ahi, bhi[j], acc[i][j], 0, 0, 0);
      }
    }
    __syncthreads();
  }

  float scl = 1.0f;
  if (RES) scl = scale_ptr ? *scale_ptr : 1.0f;
  const int er = (lane >> 4) << 2;       // 0,4,8,12
#pragma unroll
  for (int i = 0; i < 4; ++i) {
#pragma unroll
    for (int p = 0; p < 4; ++p) {
      const size_t row = (size_t)(m0 + wr + i * 16 + er + p);
#pragma unroll
      for (int j = 0; j < 4; ++j) {
        const int col = n0 + wc + j * 16 + fr;
        float v = acc[i][j][p];
        if (RELU) v = fmaxf(v, 0.0f);
        if (RES)  v = fmaf(v, scl, res[row * (size_t)ldc + col]);
        C[row * (size_t)ldc + col] = v;
      }
    }
  }
}

// ---------------------------------------------------------------------------
// Weight prep kernels (unchanged, HW-validated)
// ---------------------------------------------------------------------------
__global__ __launch_bounds__(256) void conv_w_t_kernel(
    const float* __restrict__ W, short* __restrict__ out, int K, int N)
{
  __shared__ float t[32][33];
  const int k0 = blockIdx.x * 32, n0 = blockIdx.y * 32;
  const int tx = threadIdx.x & 31, ty = threadIdx.x >> 5;   // 32 x 8
  for (int r = ty; r < 32; r += 8)
    t[r][tx] = W[(size_t)(k0 + r) * N + n0 + tx];
  __syncthreads();
  const size_t plane = (size_t)N * K;
  for (int r = ty; r < 32; r += 8) {
    float f = t[tx][r];                       // W[k0+tx][n0+r]
    ushort h = f2bf(f);
    out[(size_t)(n0 + r) * K + k0 + tx]         = (short)h;
    out[plane + (size_t)(n0 + r) * K + k0 + tx] = (short)f2bf(f - bf2f(h));
  }
}

__global__ __launch_bounds__(256) void conv_w_kernel(
    const float* __restrict__ W, short* __restrict__ out, size_t NK)
{
  size_t i = (size_t)blockIdx.x * 256 + threadIdx.x;
  float f = W[i];
  ushort h = f2bf(f);
  out[i]      = (short)h;
  out[NK + i] = (short)f2bf(f - bf2f(h));
}

__global__ __launch_bounds__(256) void rearrange_w1_bf_kernel(
    const float* __restrict__ pw1, short* __restrict__ out)
{
  const int o = blockIdx.x;
  const size_t plane = (size_t)DD * (3 * DD);
  for (int i = threadIdx.x; i < 3 * DD; i += 256) {
    int t = i / DD, d = i - t * DD;
    float f = pw1[(size_t)o * (3 * DD) + d * 3 + t];
    ushort h = f2bf(f);
    out[(size_t)o * (3 * DD) + i]         = (short)h;
    out[plane + (size_t)o * (3 * DD) + i] = (short)f2bf(f - bf2f(h));
  }
}

// ---------------------------------------------------------------------------
// MFMA flash attention (bf16 operands, fp32 accumulate), dh=64, L=512.
// HW-validated r9 (attn dropped out of top-5; total 2229->1776us).
// ---------------------------------------------------------------------------
__global__ __launch_bounds__(256) void attn_mfma_kernel(
    const float* __restrict__ Q, const float* __restrict__ K,
    const float* __restrict__ V, float* __restrict__ O)
{
  const int bh = blockIdx.y;
  const int b = bh >> 3, h = bh & 7;
  const int q0 = blockIdx.x * 64;
  const int tid = threadIdx.x;
  const int wid  = tid >> 6;        // wave id: q-rows [wid*16, wid*16+16)
  const int lane = tid & 63;
  const int fr = lane & 15;         // frag row index
  const int fg = lane >> 4;         // frag k-group

  __shared__ short Qs[64][72];      // bf16 [q][d]
  __shared__ short Ks[32][72];      // bf16 [kcol][d]
  __shared__ short Vt[64][40];      // bf16 [d][k]  (V transposed)
  __shared__ short Ps[4][16][40];   // per-wave P [q][k]
  __shared__ __align__(16) float Al[4][16];   // per-wave alpha[q]
  __shared__ __align__(16) float Ll[4][16];   // per-wave 1/l[q]

  const size_t base = ((size_t)b * LL) * DD + (size_t)h * DHH;

  // ---- stage Q (scale 1/8 folded in), fp32 -> bf16 ----
  {
    const int row = tid >> 2, dc = (tid & 3) << 4;
    const float* qp = &Q[base + (size_t)(q0 + row) * DD + dc];
#pragma unroll
    for (int hf = 0; hf < 2; ++hf) {
      F4 a = cf4(qp)[2 * hf], c = cf4(qp)[2 * hf + 1];
      short8 s8;
#pragma unroll
      for (int e = 0; e < 4; ++e) {
        s8[e]     = (short)f2bf(a.v[e] * 0.125f);
        s8[4 + e] = (short)f2bf(c.v[e] * 0.125f);
      }
      *(short8*)&Qs[row][dc + hf * 8] = s8;
    }
  }
  __syncthreads();

  // Q fragments are invariant over the K loop: hoist.
  const short8 qf0 = *(const short8*)&Qs[wid * 16 + fr][fg * 8];
  const short8 qf1 = *(const short8*)&Qs[wid * 16 + fr][32 + fg * 8];

  float mrow = -1e30f, lrow = 0.0f;   // softmax state for q = fr (dup over fg)
  f32x4 oacc[4] = {};                 // O[q=4*fg+r][d = dt*16 + fr]

  for (int kt = 0; kt < 16; ++kt) {
    const int kbase = kt * 32;
    // ---- stage K tile bf16 [32][64] ----
    {
      const int row = tid >> 3, dc = (tid & 7) << 3;
      const float* kp = &K[base + (size_t)(kbase + row) * DD + dc];
      F4 a = cf4(kp)[0], c = cf4(kp)[1];
      short8 s8;
#pragma unroll
      for (int e = 0; e < 4; ++e) {
        s8[e]     = (short)f2bf(a.v[e]);
        s8[4 + e] = (short)f2bf(c.v[e]);
      }
      *(short8*)&Ks[row][dc] = s8;
    }
    // ---- stage V transposed: thread owns 2 k-cols x 4 d-rows ----
    {
      const int kp2 = (tid & 15) * 2, dq = tid >> 4;   // d = dq*4
      const float* vp0 = &V[base + (size_t)(kbase + kp2) * DD + dq * 4];
      const float* vp1 = vp0 + DD;
      F4 a = *cf4(vp0), c = *cf4(vp1);
#pragma unroll
      for (int e = 0; e < 4; ++e) {
        unsigned pk = (unsigned)f2bf(a.v[e]) | ((unsigned)f2bf(c.v[e]) << 16);
        *(unsigned*)&Vt[dq * 4 + e][kp2] = pk;
      }
    }
    __syncthreads();

    // ---- S^T tiles: C[m=kcol][n=q], contraction over d (2 steps) ----
    f32x4 st0 = {}, st1 = {};
    {
      short8 kf;
      kf  = *(const short8*)&Ks[fr][fg * 8];
      st0 = __builtin_amdgcn_mfma_f32_16x16x32_bf16(kf, qf0, st0, 0, 0, 0);
      kf  = *(const short8*)&Ks[fr][32 + fg * 8];
      st0 = __builtin_amdgcn_mfma_f32_16x16x32_bf16(kf, qf1, st0, 0, 0, 0);
      kf  = *(const short8*)&Ks[16 + fr][fg * 8];
      st1 = __builtin_amdgcn_mfma_f32_16x16x32_bf16(kf, qf0, st1, 0, 0, 0);
      kf  = *(const short8*)&Ks[16 + fr][32 + fg * 8];
      st1 = __builtin_amdgcn_mfma_f32_16x16x32_bf16(kf, qf1, st1, 0, 0, 0);
    }

    // ---- online softmax for q = fr; 8 scores/lane ----
    float pmax = st0[0];
#pragma unroll
    for (int r = 1; r < 4; ++r) pmax = fmaxf(pmax, st0[r]);
#pragma unroll
    for (int r = 0; r < 4; ++r) pmax = fmaxf(pmax, st1[r]);
    pmax = fmaxf(pmax, __shfl_xor(pmax, 16));
    pmax = fmaxf(pmax, __shfl_xor(pmax, 32));
    const float mnew  = fmaxf(mrow, pmax);
    const float alpha = __expf(mrow - mnew);
    float p[8], psum = 0.0f;
#pragma unroll
    for (int r = 0; r < 4; ++r) { p[r]     = __expf(st0[r] - mnew); psum += p[r]; }
#pragma unroll
    for (int r = 0; r < 4; ++r) { p[4 + r] = __expf(st1[r] - mnew); psum += p[4 + r]; }
    psum += __shfl_xor(psum, 16);
    psum += __shfl_xor(psum, 32);
    lrow = lrow * alpha + psum;
    mrow = mnew;

    // ---- P -> LDS (bf16): lane holds kcols {4fg+r} and {16+4fg+r} for q=fr
    {
      short4v pk0, pk1;
#pragma unroll
      for (int r = 0; r < 4; ++r) {
        pk0[r] = (short)f2bf(p[r]);
        pk1[r] = (short)f2bf(p[4 + r]);
      }
      *(short4v*)&Ps[wid][fr][4 * fg]      = pk0;
      *(short4v*)&Ps[wid][fr][16 + 4 * fg] = pk1;
    }
    if (fg == 0) Al[wid][fr] = alpha;
    __syncthreads();

    // ---- rescale O, then PV: O[q][d] += P[q][k] * V[k][d] ----
    {
      F4 av = *cf4(&Al[wid][fg * 4]);     // alpha for rows q = 4fg+r
#pragma unroll
      for (int dt = 0; dt < 4; ++dt)
#pragma unroll
        for (int r = 0; r < 4; ++r) oacc[dt][r] *= av.v[r];

      short8 pf = *(const short8*)&Ps[wid][fr][fg * 8];
#pragma unroll
      for (int dt = 0; dt < 4; ++dt) {
        short8 vf = *(const short8*)&Vt[dt * 16 + fr][fg * 8];
        oacc[dt] = __builtin_amdgcn_mfma_f32_16x16x32_bf16(pf, vf, oacc[dt], 0, 0, 0);
      }
    }
    __syncthreads();   // before restaging K/Vt
  }

  // ---- epilogue: scale by 1/l (cross lane-layout via LDS) ----
  if (fg == 0) Ll[wid][fr] = 1.0f / lrow;
  __syncthreads();
  F4 lv = *cf4(&Ll[wid][fg * 4]);
#pragma unroll
  for (int r = 0; r < 4; ++r) {
    const size_t row = (size_t)(q0 + wid * 16 + 4 * fg + r);
#pragma unroll
    for (int dt = 0; dt < 4; ++dt)
      O[base + row * DD + dt * 16 + fr] = oacc[dt][r] * lv.v[r];
  }
}

// ---------------------------------------------------------------------------
// Kernel-size predictor head. One block per sample.
// ---------------------------------------------------------------------------
__global__ __launch_bounds__(256) void kp_head_kernel(
    const float* __restrict__ x, const float* __restrict__ w1,
    const float* __restrict__ b1, const float* __restrict__ w2,
    const float* __restrict__ b2, int* __restrict__ kout)
{
  const int b = blockIdx.x, tid = threadIdx.x;
  __shared__ float xg[DD];
  __shared__ float h1s[256];
  __shared__ float red[256];
  const float* xb = x + (size_t)b * LL * DD;

  for (int d = tid; d < DD; d += 256) {
    float s = 0.0f;
    for (int l = 0; l < LL; ++l) s += xb[(size_t)l * DD + d];
    xg[d] = s * (1.0f / (float)LL);
  }
  __syncthreads();
  {
    float s = b1[tid];
    for (int d = 0; d < DD; ++d) s = fmaf(xg[d], w1[d * 256 + tid], s);
    h1s[tid] = fmaxf(s, 0.0f);
  }
  __syncthreads();
  red[tid] = h1s[tid] * w2[tid];
  __syncthreads();
  for (int st = 128; st > 0; st >>= 1) {
    if (tid < st) red[tid] += red[tid + st];
    __syncthreads();
  }
  if (tid == 0) {
    float z = red[0] + b2[0];
    float kf = 45.0f / (1.0f + expf(-z)) + 5.0f;
    int k = (int)rintf(kf);          // round-half-to-even, matches jnp.round
    if (k > 50) k = 50;
    if (k < 3) k = 3;
    if ((k & 1) == 0) k -= 1;
    if (k < 3) k = 3;
    kout[b] = k;
  }
}

// Per (b,d) softmax over first k taps of dw[d,:]; store transposed [B][KMAX][D]
__global__ __launch_bounds__(256) void softmax_w_kernel(
    const float* __restrict__ dw, const int* __restrict__ kvals,
    float* __restrict__ wT)
{
  const int b = blockIdx.y;
  const int d = blockIdx.x * 256 + threadIdx.x;
  const int k = kvals[b];
  const float* row = dw + (size_t)d * KMAXC;
  float mx = -1e30f;
  for (int j = 0; j < k; ++j) mx = fmaxf(mx, row[j]);
  float ssum = 0.0f;
  for (int j = 0; j < k; ++j) ssum += __expf(row[j] - mx);
  float inv = 1.0f / ssum;
  float* w = wT + (size_t)b * KMAXC * DD + d;
  for (int j = 0; j < k; ++j) w[(size_t)j * DD] = __expf(row[j] - mx) * inv;
}

// trend[b,l,d] = sum_{j<k} wT[b,j,d] * x[b, clamp(l-half+j), d]
__global__ __launch_bounds__(512) void trend_kernel(
    const float* __restrict__ xin, const float* __restrict__ wT,
    const int* __restrict__ kvals, float* __restrict__ tr)
{
  const int b = blockIdx.y, l = blockIdx.x, d = threadIdx.x;
  const int k = kvals[b], half = k >> 1;
  const float* xb = xin + (size_t)b * LL * DD;
  const float* w = wT + (size_t)b * KMAXC * DD + d;
  float t = 0.0f;
  for (int j = 0; j < k; ++j) {
    int li = l - half + j;
    li = li < 0 ? 0 : (li > LL - 1 ? LL - 1 : li);
    t = fmaf(w[(size_t)j * DD], xb[(size_t)li * DD + d], t);
  }
  tr[((size_t)b * LL + l) * DD + d] = t;
}

// xout = xin - tr;  tacc = (first ? tr : tacc + tr)
__global__ __launch_bounds__(256) void apply_kernel(
    const float* __restrict__ xin, const float* __restrict__ tr,
    float* __restrict__ xout, float* __restrict__ tacc, int first)
{
  size_t i = (size_t)blockIdx.x * blockDim.x + threadIdx.x; // F4 idx
  F4 xv = cf4(xin)[i];
  F4 tv = cf4(tr)[i];
  F4 o, a;
  if (first) {
#pragma unroll
    for (int c = 0; c < 4; ++c) { o.v[c] = xv.v[c] - tv.v[c]; a.v[c] = tv.v[c]; }
  } else {
    F4 ta = cf4((const float*)tacc)[i];
#pragma unroll
    for (int c = 0; c < 4; ++c) { o.v[c] = xv.v[c] - tv.v[c]; a.v[c] = ta.v[c] + tv.v[c]; }
  }
  pf4(xout)[i] = o;
  pf4(tacc)[i] = a;
}

// aaug[b,l, t*D+d] = tacc[b, (l-1+t) mod L, d]   (circular)
__global__ __launch_bounds__(512) void build_aaug_kernel(
    const float* __restrict__ tacc, float* __restrict__ aaug)
{
  const int b = blockIdx.y, l = blockIdx.x, d = threadIdx.x;
  float* outp = aaug + ((size_t)b * LL + l) * (3 * DD);
  const float* tb = tacc + (size_t)b * LL * DD;
#pragma unroll
  for (int t = 0; t < 3; ++t) {
    int li = (l - 1 + t + LL) & (LL - 1);
    outp[t * DD + d] = tb[(size_t)li * DD + d];
  }
}

// ---------------------------------------------------------------------------
extern "C" void kernel_launch(void* const* d_in, const int* in_sizes, int n_in,
                              void* d_out, int out_size, void* d_ws, size_t ws_size,
                              hipStream_t stream)
{
  const float* x      = (const float*)d_in[0];
  const float* cross  = (const float*)d_in[1];
  const float* wq_s   = (const float*)d_in[2];
  const float* wk_s   = (const float*)d_in[3];
  const float* wv_s   = (const float*)d_in[4];
  const float* wo_s   = (const float*)d_in[5];
  const float* wq_c   = (const float*)d_in[6];
  const float* wk_c   = (const float*)d_in[7];
  const float* wv_c   = (const float*)d_in[8];
  const float* wo_c   = (const float*)d_in[9];
  const float* conv1  = (const float*)d_in[10];
  const float* conv2  = (const float*)d_in[11];
  const float* dw     = (const float*)d_in[12];
  const float* kp_w1  = (const float*)d_in[13];
  const float* kp_b1  = (const float*)d_in[14];
  const float* kp_w2  = (const float*)d_in[15];
  const float* kp_b2  = (const float*)d_in[16];
  const float* pw1    = (const float*)d_in[17];
  const float* pw2    = (const float*)d_in[18];
  const float* sscale = (const float*)d_in[19];
  const float* cscale = (const float*)d_in[20];

  float* out = (float*)d_out;
  float* ws  = (float*)d_ws;

  const size_t NBLD = (size_t)BB * LL * DD;   // 8,388,608 floats (32 MiB)
  float* xcur   = ws;                // persistent residual stream
  float* tacc   = ws + NBLD;         // persistent trend accumulator
  float* big    = ws + 2 * NBLD;     // 4*NBLD region, reused per phase
  float* qb     = big;
  float* kb     = big + NBLD;
  float* vb     = big + 2 * NBLD;
  float* attno  = big;               // attention O in-place over Q
  float* hidden = big;               // FFN hidden: exactly 4*NBLD
  float* aaug   = big;               // [B*L, 3D]: 3*NBLD
  float* hconv  = big + 3 * NBLD;
  float* trendb = big;               // trend scratch
  float* smallp = ws + 6 * NBLD;
  float* wT     = smallp;                    // B*KMAX*D = 819200
  int*   kvals  = (int*)(smallp + 819200);   // 32 ints (64 floats reserved)
  float* wbase  = smallp + 819200 + 64;
  // Split-bf16 weight buffers ([2][N][K] shorts == N*K floats each):
  short* w1r_sp = (short*)(wbase);                         // 512x1536: 786432 fl
  short* wsp[8];                                           // 8 attn weights
  for (int i = 0; i < 8; ++i) wsp[i] = (short*)(wbase + 786432 + (size_t)i * 262144);
  short* c1_sp  = (short*)(wbase + 786432 + 8 * 262144);             // 1048576 fl
  short* c2_sp  = (short*)(wbase + 786432 + 8 * 262144 + 1048576);   // 1048576 fl
  short* pw2_sp = (short*)(wbase + 786432 + 8 * 262144 + 2 * 1048576); // 262144 fl

  const int M = BB * LL;  // 16384
  const dim3 g512(4, 128), gFF1(16, 128), gBL(LL, BB), gSM(2, BB), gWT(16, 16);

  // ---- weight prep ----
  conv_w_t_kernel<<<gWT,256,0,stream>>>(wq_s, wsp[0], DD, DD);
  conv_w_t_kernel<<<gWT,256,0,stream>>>(wk_s, wsp[1], DD, DD);
  conv_w_t_kernel<<<gWT,256,0,stream>>>(wv_s, wsp[2], DD, DD);
  conv_w_t_kernel<<<gWT,256,0,stream>>>(wo_s, wsp[3], DD, DD);
  conv_w_t_kernel<<<gWT,256,0,stream>>>(wq_c, wsp[4], DD, DD);
  conv_w_t_kernel<<<gWT,256,0,stream>>>(wk_c, wsp[5], DD, DD);
  conv_w_t_kernel<<<gWT,256,0,stream>>>(wv_c, wsp[6], DD, DD);
  conv_w_t_kernel<<<gWT,256,0,stream>>>(wo_c, wsp[7], DD, DD);
  conv_w_kernel<<<4096,256,0,stream>>>(conv1, c1_sp, (size_t)DFF * DD);
  conv_w_kernel<<<4096,256,0,stream>>>(conv2, c2_sp, (size_t)DD * DFF);
  conv_w_kernel<<<1024,256,0,stream>>>(pw2, pw2_sp, (size_t)DD * DD);
  rearrange_w1_bf_kernel<<<512,256,0,stream>>>(pw1, w1r_sp);

  // ---- self attention ----
  gemm_bf<false,false><<<g512,256,0,stream>>>(x, DD, wsp[0], qb, DD, nullptr, nullptr, M, DD, DD);
  gemm_bf<false,false><<<g512,256,0,stream>>>(x, DD, wsp[1], kb, DD, nullptr, nullptr, M, DD, DD);
  gemm_bf<false,false><<<g512,256,0,stream>>>(x, DD, wsp[2], vb, DD, nullptr, nullptr, M, DD, DD);
  attn_mfma_kernel<<<dim3(8, BB*HH),256,0,stream>>>(qb, kb, vb, attno);
  gemm_bf<false,true ><<<g512,256,0,stream>>>(attno, DD, wsp[3], xcur, DD, x, sscale, M, DD, DD);

  // ---- decomp 1 ----
  kp_head_kernel<<<BB,256,0,stream>>>(xcur, kp_w1, kp_b1, kp_w2, kp_b2, kvals);
  softmax_w_kernel<<<gSM,256,0,stream>>>(dw, kvals, wT);
  trend_kernel<<<gBL,512,0,stream>>>(xcur, wT, kvals, trendb);
  apply_kernel<<<8192,256,0,stream>>>(xcur, trendb, xcur, tacc, 1);

  // ---- cross attention ----
  gemm_bf<false,false><<<g512,256,0,stream>>>(xcur, DD, wsp[4], qb, DD, nullptr, nullptr, M, DD, DD);
  gemm_bf<false,false><<<g512,256,0,stream>>>(cross, DD, wsp[5], kb, DD, nullptr, nullptr, M, DD, DD);
  gemm_bf<false,false><<<g512,256,0,stream>>>(cross, DD, wsp[6], vb, DD, nullptr, nullptr, M, DD, DD);
  attn_mfma_kernel<<<dim3(8, BB*HH),256,0,stream>>>(qb, kb, vb, attno);
  gemm_bf<false,true ><<<g512,256,0,stream>>>(attno, DD, wsp[7], xcur, DD, xcur, cscale, M, DD, DD);

  // ---- decomp 2 ----
  kp_head_kernel<<<BB,256,0,stream>>>(xcur, kp_w1+131072, kp_b1+256, kp_w2+256, kp_b2+1, kvals);
  softmax_w_kernel<<<gSM,256,0,stream>>>(dw+25600, kvals, wT);
  trend_kernel<<<gBL,512,0,stream>>>(xcur, wT, kvals, trendb);
  apply_kernel<<<8192,256,0,stream>>>(xcur, trendb, xcur, tacc, 0);

  // ---- conv FFN ----
  gemm_bf<true ,false><<<gFF1,256,0,stream>>>(xcur, DD, c1_sp, hidden, DFF, nullptr, nullptr, M, DFF, DD);
  gemm_bf<false,true ><<<g512,256,0,stream>>>(hidden, DFF, c2_sp, xcur, DD, xcur, nullptr, M, DD, DFF);

  // ---- decomp 3 (x3 straight to d_out) ----
  kp_head_kernel<<<BB,256,0,stream>>>(xcur, kp_w1+262144, kp_b1+512, kp_w2+512, kp_b2+2, kvals);
  softmax_w_kernel<<<gSM,256,0,stream>>>(dw+51200, kvals, wT);
  trend_kernel<<<gBL,512,0,stream>>>(xcur, wT, kvals, trendb);
  apply_kernel<<<8192,256,0,stream>>>(xcur, trendb, out, tacc, 0);

  // ---- trend projection ----
  build_aaug_kernel<<<gBL,512,0,stream>>>(tacc, aaug);
  gemm_bf<true ,false><<<g512,256,0,stream>>>(aaug, 3*DD, w1r_sp, hconv, DD, nullptr, nullptr, M, DD, 3*DD);
  gemm_bf<false,false><<<g512,256,0,stream>>>(hconv, DD, pw2_sp, out+NBLD, DD, nullptr, nullptr, M, DD, DD);
}